// Round 6
// baseline (567.143 us; speedup 1.0000x reference)
//
#include <hip/hip_runtime.h>
#include <cstdint>

// B=16, C=64, Np=128, D=128, HT=4 (dh=32), HS=4, F=128, DK=64, TOPK=8

typedef __attribute__((ext_vector_type(8)))  short bf16x8;
typedef __attribute__((ext_vector_type(16))) float f32x16;
#define MFMA32(a, b, c) __builtin_amdgcn_mfma_f32_32x32x16_bf16((a), (b), (c), 0, 0, 0)

__device__ __forceinline__ unsigned short f2bf(float f) {
    unsigned int u = __float_as_uint(f);
    u += 0x7fffu + ((u >> 16) & 1u);
    return (unsigned short)(u >> 16);
}
__device__ __forceinline__ float bf2f(unsigned short u) {
    return __uint_as_float(((unsigned int)u) << 16);
}

__device__ __forceinline__ bf16x8 lds_frag(const unsigned short* p) {
    union { bf16x8 v; ushort4 h[2]; } u;
    u.h[0] = *(const ushort4*)p;
    u.h[1] = *(const ushort4*)(p + 4);
    return u.v;
}
__device__ __forceinline__ bf16x8 gfrag(const unsigned short* p) {
    union { bf16x8 v; uint4 u; } t;
    t.u = *(const uint4*)p;
    return t.v;
}

// C/D layout for 32x32x16: col = lane&31, row = (reg&3) + 8*(reg>>2) + 4*(lane>>5)
__device__ __forceinline__ int rowmap(int r, int hl) { return (r & 3) + 8 * (r >> 2) + 4 * hl; }

__device__ __forceinline__ unsigned int pk2(float lo, float hi) {
    return (unsigned int)f2bf(lo) | ((unsigned int)f2bf(hi) << 16);
}

// Build an MFMA A/B fragment (16-wide k-chunk) from a C-layout f32x16.
// Partner 4-groups fetched with v_permlane32_swap_b32 (lanes[0:31] <-> lanes[32:63]).
template<int B>
__device__ __forceinline__ bf16x8 pack_frag(const f32x16& p) {
    unsigned int a0 = pk2(p[B + 0], p[B + 1]);
    unsigned int a1 = pk2(p[B + 2], p[B + 3]);
    unsigned int b0 = pk2(p[B + 4], p[B + 5]);
    unsigned int b1 = pk2(p[B + 6], p[B + 7]);
    asm("v_permlane32_swap_b32 %0, %1" : "+v"(b0), "+v"(a0));
    asm("v_permlane32_swap_b32 %0, %1" : "+v"(b1), "+v"(a1));
    union { bf16x8 v; unsigned int w[4]; } u;
    u.w[0] = a0; u.w[1] = a1; u.w[2] = b0; u.w[3] = b1;
    return u.v;
}

// ---------------------------------------------------------------------------
__global__ void wconv_kernel(const float* __restrict__ wqkv, const float* __restrict__ wout,
                             const float* __restrict__ w1, const float* __restrict__ w2,
                             const float* __restrict__ gw,
                             unsigned short* __restrict__ dst) {
    int i = blockIdx.x * 256 + threadIdx.x;   // 262144 total
    float v;
    if (i < 49152)       v = wqkv[i];
    else if (i < 65536)  v = wout[i - 49152];
    else if (i < 131072) v = w1[i - 65536];
    else if (i < 196608) v = w2[i - 131072];
    else                 v = gw[i - 196608];
    dst[i] = f2bf(v);
}

// ---------------------------------------------------------------------------
__global__ void wa_kernel(const float* __restrict__ gw, const float* __restrict__ asw,
                          const float* __restrict__ adw,
                          float* __restrict__ waS, float* __restrict__ waD) {
    int t = blockIdx.x * 256 + threadIdx.x;   // 1024
    int h = t >> 8, d = (t >> 1) & 127, which = t & 1;
    const float* av = which ? adw : asw;
    float s = 0.f;
    for (int f = 0; f < 128; f++) s += av[h * 128 + f] * gw[(h * 128 + f) * 128 + d];
    (which ? waD : waS)[h * 128 + d] = s;
}

// ---------------------------------------------------------------------------
// Fused temporal block (unchanged from R5 — verified at 243 us).
#define QKV_STAGE(H, KBB, VTB) do {                                              \
    f32x16 accq, acck, accv;                                                     \
    _Pragma("unroll") for (int r = 0; r < 16; r++)                               \
        accq[r] = bqkv[(H) * 32 + rowmap(r, hl)];                                \
    float bk_ = bqkv[128 + (H) * 32 + l31];                                      \
    float bv_ = bqkv[256 + (H) * 32 + l31];                                      \
    _Pragma("unroll") for (int r = 0; r < 16; r++) { acck[r] = bk_; accv[r] = bv_; } \
    const unsigned short* wq_ = wqkv_b + ((H) * 32 + l31) * 128 + hl * 8;        \
    const unsigned short* wk_ = wqkv_b + (128 + (H) * 32 + l31) * 128 + hl * 8;  \
    const unsigned short* wv_ = wqkv_b + (256 + (H) * 32 + l31) * 128 + hl * 8;  \
    _Pragma("unroll") for (int k0 = 0; k0 < 128; k0 += 16) {                     \
        bf16x8 a_ = lds_frag(&RA[myrow][k0 + hl * 8]);                           \
        accq = MFMA32(gfrag(wq_ + k0), a_, accq);  /* Q^T: rows=dh, cols=toks */ \
        acck = MFMA32(a_, gfrag(wk_ + k0), acck);                                \
        accv = MFMA32(a_, gfrag(wv_ + k0), accv);                                \
    }                                                                            \
    _Pragma("unroll") for (int r = 0; r < 16; r++) {                             \
        int tok_ = wv * 32 + rowmap(r, hl);                                      \
        KBB[tok_][l31] = f2bf(acck[r]);                                          \
        VTB[l31][tok_] = f2bf(accv[r]);                                          \
    }                                                                            \
    qf0_ = pack_frag<0>(accq);                                                   \
    qf1_ = pack_frag<8>(accq);                                                   \
} while (0)

#define ATTN_PHASE(H, KBB, VTB, NEXTQKV) do {                                    \
    f32x16 sacc[4];                                                              \
    _Pragma("unroll") for (int t = 0; t < 4; t++)                                \
    _Pragma("unroll") for (int r = 0; r < 16; r++) sacc[t][r] = 0.f;             \
    _Pragma("unroll") for (int t = 0; t < 4; t++) {                              \
        bf16x8 ka0 = lds_frag(&KBB[t * 32 + l31][hl * 8]);                       \
        sacc[t] = MFMA32(ka0, qf0_, sacc[t]);                                    \
        bf16x8 ka1 = lds_frag(&KBB[t * 32 + l31][16 + hl * 8]);                  \
        sacc[t] = MFMA32(ka1, qf1_, sacc[t]);                                    \
    }                                                                            \
    NEXTQKV;                                                                     \
    const float scale_ = 0.17677669529663687f;   /* 1/sqrt(32) */                \
    float m0 = -1e30f;                                                           \
    _Pragma("unroll") for (int t = 0; t < 4; t++)                                \
    _Pragma("unroll") for (int r = 0; r < 16; r++) m0 = fmaxf(m0, sacc[t][r]);   \
    m0 = fmaxf(m0, __shfl_xor(m0, 32));                                          \
    float ssum = 0.f;                                                            \
    _Pragma("unroll") for (int t = 0; t < 4; t++)                                \
    _Pragma("unroll") for (int r = 0; r < 16; r++) {                             \
        float e_ = __expf(scale_ * (sacc[t][r] - m0));                           \
        sacc[t][r] = e_; ssum += e_;                                             \
    }                                                                            \
    ssum += __shfl_xor(ssum, 32);                                                \
    float rinv_ = 1.f / ssum;                                                    \
    _Pragma("unroll") for (int t = 0; t < 4; t++)                                \
    _Pragma("unroll") for (int r = 0; r < 16; r++) sacc[t][r] *= rinv_;          \
    f32x16 oacc;                                                                 \
    _Pragma("unroll") for (int r = 0; r < 16; r++) oacc[r] = 0.f;                \
    _Pragma("unroll") for (int t = 0; t < 4; t++) {                              \
        bf16x8 pf0 = pack_frag<0>(sacc[t]);                                      \
        bf16x8 v0_ = lds_frag(&VTB[l31][t * 32 + hl * 8]);                       \
        oacc = MFMA32(pf0, v0_, oacc);                                           \
        bf16x8 pf1 = pack_frag<8>(sacc[t]);                                      \
        bf16x8 v1_ = lds_frag(&VTB[l31][t * 32 + 16 + hl * 8]);                  \
        oacc = MFMA32(pf1, v1_, oacc);                                           \
    }                                                                            \
    _Pragma("unroll") for (int j = 0; j < 8; j++)                                \
        opk[H][j] = pk2(oacc[2*j], oacc[2*j+1]);                                 \
} while (0)

__global__ __launch_bounds__(256, 2)
void temporal_kernel(const float* __restrict__ Hin,
                     const unsigned short* __restrict__ wqkv_b, const float* __restrict__ bqkv,
                     const unsigned short* __restrict__ wout_b, const float* __restrict__ bout,
                     const float* __restrict__ g1, const float* __restrict__ b1,
                     const float* __restrict__ g2, const float* __restrict__ b2,
                     const unsigned short* __restrict__ w1_b, const float* __restrict__ bf1,
                     const unsigned short* __restrict__ w2_b, const float* __restrict__ bf2,
                     const float* __restrict__ tg, const float* __restrict__ tb,
                     float* __restrict__ Htemp, float* __restrict__ Hs) {
    // Region A (33792 B): hb (LN1 out) -> O (attn out) -> h2b (LN2 out). Wave-private rows.
    __shared__ unsigned short RA[128][132];
    // Region B (35328 B): attn dbuf {kb0,vT0,kb1,vT1} -> ffn {rscr | hsred}
    __shared__ double RBd[4416];
    unsigned short (*kb0)[36]  = (unsigned short(*)[36])RBd;                       // [tok][dh]
    unsigned short (*vT0)[132] = (unsigned short(*)[132])((char*)RBd + 9216);      // [d][tok]
    unsigned short (*kb1)[36]  = (unsigned short(*)[36])((char*)RBd + 17664);
    unsigned short (*vT1)[132] = (unsigned short(*)[132])((char*)RBd + 26880);
    unsigned short (*rscr)[32][36] = (unsigned short(*)[32][36])RBd;               // [0..9216) = kb0 region
    float (*hsred)[128] = (float(*)[128])((char*)RBd + 9216);                      // [9216..11264) = vT0 region

    const int n = blockIdx.x;
    const int tid = threadIdx.x;
    const int lane = tid & 63;
    const int wv = tid >> 6;
    const int hl = lane >> 5;
    const int l31 = lane & 31;
    const int myrow = wv * 32 + l31;

    // ---- LN1 (wave-private rows: tid>>1 maps wave w to rows w*32..w*32+31) ----
    {
        int row = tid >> 1, hf = tid & 1;
        const float* src = Hin + ((long)n * 128 + row) * 128 + hf * 64;
        float xv[64];
        float s = 0.f, qs = 0.f;
#pragma unroll
        for (int i = 0; i < 64; i += 4) {
            float4 t = *(const float4*)(src + i);
            xv[i] = t.x; xv[i+1] = t.y; xv[i+2] = t.z; xv[i+3] = t.w;
        }
#pragma unroll
        for (int i = 0; i < 64; i++) { s += xv[i]; qs += xv[i] * xv[i]; }
        s += __shfl_xor(s, 1); qs += __shfl_xor(qs, 1);
        float mu = s * 0.0078125f;
        float rs = rsqrtf(fmaxf(qs * 0.0078125f - mu * mu, 0.f) + 1e-5f);
#pragma unroll
        for (int i = 0; i < 64; i++) {
            int d = hf * 64 + i;
            RA[row][d] = f2bf((xv[i] - mu) * rs * g1[d] + b1[d]);
        }
    }
    // no barrier: RA rows are wave-private for QKV A-reads

    unsigned int opk[4][8];   // O, bf16-packed, per head (all indices literal)
    bf16x8 qf0_, qf1_;        // current head's Q fragments

    // ---- pipelined head loop: 1 barrier/head; QKV(h+1) overlaps phase h ----
    QKV_STAGE(0, kb0, vT0);
    __syncthreads();                                   // kb0/vT0 cross-wave
    ATTN_PHASE(0, kb0, vT0, QKV_STAGE(1, kb1, vT1));
    __syncthreads();                                   // kb1/vT1 ready; kb0/vT0 reads done
    ATTN_PHASE(1, kb1, vT1, QKV_STAGE(2, kb0, vT0));
    __syncthreads();
    ATTN_PHASE(2, kb0, vT0, QKV_STAGE(3, kb1, vT1));
    __syncthreads();
    ATTN_PHASE(3, kb1, vT1, (void)0);
    // no barrier: remainder touches only wave-private RA rows + rscr[wv] (kb0
    // region, disjoint from the kb1/vT1 still being read by slower waves).

    // ---- O (packed regs) -> RA (hb dead; wave-private rows) ----
#pragma unroll
    for (int h = 0; h < 4; h++)
#pragma unroll
        for (int j = 0; j < 8; j++) {
            int tok0 = wv * 32 + rowmap(2*j,     hl);
            int tok1 = wv * 32 + rowmap(2*j + 1, hl);
            RA[tok0][h * 32 + l31] = (unsigned short)(opk[h][j] & 0xffffu);
            RA[tok1][h * 32 + l31] = (unsigned short)(opk[h][j] >> 16);
        }

    // ---- x = x0 + bout + O @ Wout^T ----
    f32x16 acc[4];
#pragma unroll
    for (int t = 0; t < 4; t++) {
        float bo = bout[t * 32 + l31];
#pragma unroll
        for (int r = 0; r < 16; r++) {
            int tok = wv * 32 + rowmap(r, hl);
            acc[t][r] = Hin[((long)n * 128 + tok) * 128 + t * 32 + l31] + bo;
        }
    }
#pragma unroll
    for (int k0 = 0; k0 < 128; k0 += 16) {
        bf16x8 a = lds_frag(&RA[myrow][k0 + hl * 8]);
#pragma unroll
        for (int t = 0; t < 4; t++) {
            bf16x8 b = gfrag(wout_b + (t * 32 + l31) * 128 + k0 + hl * 8);
            acc[t] = MFMA32(a, b, acc[t]);
        }
    }

    // ---- LN2 -> RA (h2b; O dead, wave-private rows) ----
#pragma unroll
    for (int r = 0; r < 16; r++) {
        float s = acc[0][r] + acc[1][r] + acc[2][r] + acc[3][r];
#pragma unroll
        for (int d = 1; d < 32; d <<= 1) s += __shfl_xor(s, d);
        float mu = s * 0.0078125f;
        float q = 0.f;
#pragma unroll
        for (int t = 0; t < 4; t++) { float dv = acc[t][r] - mu; q += dv * dv; }
#pragma unroll
        for (int d = 1; d < 32; d <<= 1) q += __shfl_xor(q, d);
        float rs = rsqrtf(q * 0.0078125f + 1e-5f);
        int row = wv * 32 + rowmap(r, hl);
#pragma unroll
        for (int t = 0; t < 4; t++) {
            int col = t * 32 + l31;
            RA[row][col] = f2bf((acc[t][r] - mu) * rs * g2[col] + b2[col]);
        }
    }

    // acc := x + bf2 in place
#pragma unroll
    for (int t = 0; t < 4; t++) {
        float bv = bf2[t * 32 + l31];
#pragma unroll
        for (int r = 0; r < 16; r++) acc[t][r] += bv;
    }

    // ---- FFN in 4 K-chunks of 128; parallel racc tiles, relu via per-wave rscr ----
    for (int j = 0; j < 4; j++) {
        f32x16 racc[4];
#pragma unroll
        for (int t = 0; t < 4; t++) {
            float bv = bf1[j * 128 + t * 32 + l31];
#pragma unroll
            for (int r = 0; r < 16; r++) racc[t][r] = bv;
        }
#pragma unroll
        for (int k0 = 0; k0 < 128; k0 += 16) {
            bf16x8 a = lds_frag(&RA[myrow][k0 + hl * 8]);   // h2b
#pragma unroll
            for (int t = 0; t < 4; t++) {
                bf16x8 b = gfrag(w1_b + (j * 128 + t * 32 + l31) * 128 + k0 + hl * 8);
                racc[t] = MFMA32(a, b, racc[t]);
            }
        }
#pragma unroll
        for (int t = 0; t < 4; t++) {
#pragma unroll
            for (int r = 0; r < 16; r++)
                rscr[wv][rowmap(r, hl)][l31] = f2bf(fmaxf(racc[t][r], 0.f));
#pragma unroll
            for (int kk = 0; kk < 32; kk += 16) {
                bf16x8 a = lds_frag(&rscr[wv][l31][kk + hl * 8]);
#pragma unroll
                for (int tp = 0; tp < 4; tp++) {
                    bf16x8 b = gfrag(w2_b + (tp * 32 + l31) * 512 + j * 128 + t * 32 + kk + hl * 8);
                    acc[tp] = MFMA32(a, b, acc[tp]);
                }
            }
        }
    }

    // ---- H_temp = LN(x0 + x', tg, tb); accumulate Hs column sums ----
#pragma unroll
    for (int t = 0; t < 4; t++)
#pragma unroll
        for (int r = 0; r < 16; r++) {
            int tok = wv * 32 + rowmap(r, hl);
            acc[t][r] += Hin[((long)n * 128 + tok) * 128 + t * 32 + l31];
        }
    float* outf = Htemp + (long)n * 16384;
    float cs0 = 0.f, cs1 = 0.f, cs2 = 0.f, cs3 = 0.f;
#pragma unroll
    for (int r = 0; r < 16; r++) {
        float s = acc[0][r] + acc[1][r] + acc[2][r] + acc[3][r];
#pragma unroll
        for (int d = 1; d < 32; d <<= 1) s += __shfl_xor(s, d);
        float mu = s * 0.0078125f;
        float q = 0.f;
#pragma unroll
        for (int t = 0; t < 4; t++) { float dv = acc[t][r] - mu; q += dv * dv; }
#pragma unroll
        for (int d = 1; d < 32; d <<= 1) q += __shfl_xor(q, d);
        float rs = rsqrtf(q * 0.0078125f + 1e-5f);
        int tok = wv * 32 + rowmap(r, hl);
        {
            float v = (acc[0][r] - mu) * rs * tg[0 * 32 + l31] + tb[0 * 32 + l31];
            outf[tok * 128 + 0 * 32 + l31] = v;  cs0 += v;
        }
        {
            float v = (acc[1][r] - mu) * rs * tg[1 * 32 + l31] + tb[1 * 32 + l31];
            outf[tok * 128 + 1 * 32 + l31] = v;  cs1 += v;
        }
        {
            float v = (acc[2][r] - mu) * rs * tg[2 * 32 + l31] + tb[2 * 32 + l31];
            outf[tok * 128 + 2 * 32 + l31] = v;  cs2 += v;
        }
        {
            float v = (acc[3][r] - mu) * rs * tg[3 * 32 + l31] + tb[3 * 32 + l31];
            outf[tok * 128 + 3 * 32 + l31] = v;  cs3 += v;
        }
    }
    // per-wave: sum own 16 toks + partner-half 16 toks = wave's 32 toks
    cs0 += __shfl_xor(cs0, 32); cs1 += __shfl_xor(cs1, 32);
    cs2 += __shfl_xor(cs2, 32); cs3 += __shfl_xor(cs3, 32);
    if (hl == 0) {
        hsred[wv][0 * 32 + l31] = cs0;
        hsred[wv][1 * 32 + l31] = cs1;
        hsred[wv][2 * 32 + l31] = cs2;
        hsred[wv][3 * 32 + l31] = cs3;
    }
    __syncthreads();
    if (tid < 128)
        Hs[(long)n * 128 + tid] =
            (hsred[0][tid] + hsred[1][tid] + hsred[2][tid] + hsred[3][tid]) * 0.0078125f;
}

// ---------------------------------------------------------------------------
__global__ __launch_bounds__(256)
void graph_kernel(const float* __restrict__ Hs,
                  const float* __restrict__ qw, const float* __restrict__ qb,
                  const float* __restrict__ kw, const float* __restrict__ kb,
                  const float* __restrict__ adj, unsigned long long* __restrict__ masks) {
    __shared__ float q2l[64][65];
    __shared__ float k2l[64][65];
    __shared__ float am[64][65];
    int b = blockIdx.x;
    int tid = threadIdx.x;
    {
        int r = tid & 127, jh = tid >> 7;
        int row = r & 63;
        const float* wmat = (r < 64) ? qw : kw;
        const float* bvec = (r < 64) ? qb : kb;
        const float* src = Hs + (long)(b * 64 + row) * 128;
        for (int jj = 0; jj < 32; jj++) {
            int j = jh * 32 + jj;
            const float* wrow = wmat + (long)j * 128;
            float s0 = 0.f, s1 = 0.f, s2 = 0.f, s3 = 0.f;
#pragma unroll
            for (int d = 0; d < 128; d += 4) {
                s0 += src[d] * wrow[d];     s1 += src[d+1] * wrow[d+1];
                s2 += src[d+2] * wrow[d+2]; s3 += src[d+3] * wrow[d+3];
            }
            float val = ((s0 + s1) + (s2 + s3)) + bvec[j];
            if (r < 64) q2l[row][j] = val; else k2l[row][j] = val;
        }
    }
    __syncthreads();
    {
        int c = tid & 63, eq = tid >> 6;
        for (int ee = 0; ee < 16; ee++) {
            int e = eq * 16 + ee;
            float s0 = 0.f, s1 = 0.f, s2 = 0.f, s3 = 0.f;
#pragma unroll
            for (int j = 0; j < 64; j += 4) {
                s0 += q2l[c][j]   * k2l[e][j];
                s1 += q2l[c][j+1] * k2l[e][j+1];
                s2 += q2l[c][j+2] * k2l[e][j+2];
                s3 += q2l[c][j+3] * k2l[e][j+3];
            }
            float sim = ((s0 + s1) + (s2 + s3)) * 0.125f;
            am[c][e] = tanhf(sim) + adj[c * 64 + e];
        }
    }
    __syncthreads();
    if (tid < 64) {
        int c = tid;
        unsigned long long sel = 0ull;
        for (int it = 0; it < 8; it++) {
            float best = -1e38f; int bi = 0;
            for (int e = 0; e < 64; e++) {
                float v = am[c][e];
                bool ok = (((sel >> e) & 1ull) == 0ull) && (v > best);
                best = ok ? v : best;
                bi = ok ? e : bi;
            }
            sel |= (1ull << bi);
        }
        sel &= ~(1ull << c);
        for (int e = 0; e < 64; e++)
            if (am[c][e] == 0.f) sel &= ~(1ull << e);
        masks[b * 64 + c] = sel;
    }
}

// ---------------------------------------------------------------------------
// GAT + final LN. Attention weights are xh-INDEPENDENT (e = leaky(asrc+adst)):
// computed per-lane in registers (lane owns target rs+l31 and exactly the 32
// sources its PV A-frags need; partner-half via one shfl_xor(32)). attT and
// the 3-barrier cross-wave softmax are gone. xhT double-buffered: per-head
// loop is {PV(h) + xh(h+1)} with ONE barrier. ~8 barriers/block (was ~20).
#define XH_STAGE(H, XT) do {                                                     \
    f32x16 a0_, a1_;                                                             \
    _Pragma("unroll") for (int r = 0; r < 16; r++) { a0_[r] = 0.f; a1_[r] = 0.f; } \
    const unsigned short* gwh_ = gwb + (H) * 16384;                              \
    _Pragma("unroll") for (int k0 = 0; k0 < 128; k0 += 16) {                     \
        bf16x8 af_ = lds_frag(&Htb[rs + l31][k0 + hl * 8]);                      \
        bf16x8 b0_ = gfrag(gwh_ + (cs + l31) * 128 + k0 + hl * 8);               \
        bf16x8 b1_ = gfrag(gwh_ + (cs + 32 + l31) * 128 + k0 + hl * 8);          \
        a0_ = MFMA32(af_, b0_, a0_);                                             \
        a1_ = MFMA32(af_, b1_, a1_);                                             \
    }                                                                            \
    _Pragma("unroll") for (int g = 0; g < 4; g++) {                              \
        ushort4 u0_, u1_;                                                        \
        u0_.x = f2bf(a0_[4*g]);   u0_.y = f2bf(a0_[4*g+1]);                      \
        u0_.z = f2bf(a0_[4*g+2]); u0_.w = f2bf(a0_[4*g+3]);                      \
        u1_.x = f2bf(a1_[4*g]);   u1_.y = f2bf(a1_[4*g+1]);                      \
        u1_.z = f2bf(a1_[4*g+2]); u1_.w = f2bf(a1_[4*g+3]);                      \
        int so_ = rs + 4 * hl + 8 * g;                                           \
        *(ushort4*)&XT[cs + l31][so_]      = u0_;                                \
        *(ushort4*)&XT[cs + 32 + l31][so_] = u1_;                                \
    }                                                                            \
} while (0)

#define PV_PHASE(H, XT, NEXTXH) do {                                             \
    float adv_ = adstF[H][rs + l31];   /* target t = rs + l31 */                 \
    float ev_[4][8];                                                             \
    float M_ = -1e30f;                                                           \
    _Pragma("unroll") for (int q = 0; q < 4; q++)                                \
    _Pragma("unroll") for (int j = 0; j < 8; j++) {                              \
        int s_ = q * 16 + hl * 8 + j;                                            \
        float e_ = asrcF[H][s_] + adv_;                                          \
        e_ = (e_ > 0.f) ? e_ : 0.2f * e_;                                        \
        ev_[q][j] = e_;                                                          \
        if ((mt >> s_) & 1ull) M_ = fmaxf(M_, e_);                               \
    }                                                                            \
    M_ = fmaxf(M_, __shfl_xor(M_, 32));                                          \
    float sm_ = 0.f;                                                             \
    _Pragma("unroll") for (int q = 0; q < 4; q++)                                \
    _Pragma("unroll") for (int j = 0; j < 8; j++) {                              \
        int s_ = q * 16 + hl * 8 + j;                                            \
        float w_ = ((mt >> s_) & 1ull) ? __expf(ev_[q][j] - M_) : 0.f;           \
        ev_[q][j] = w_; sm_ += w_;                                               \
    }                                                                            \
    sm_ += __shfl_xor(sm_, 32);                                                  \
    float rinv_ = (sm_ > 0.f) ? 1.f / sm_ : 0.f;                                 \
    NEXTXH;                                                                      \
    _Pragma("unroll") for (int q = 0; q < 4; q++) {                              \
        union { bf16x8 v; unsigned int w[4]; } uu_;                              \
        uu_.w[0] = pk2(ev_[q][0] * rinv_, ev_[q][1] * rinv_);                    \
        uu_.w[1] = pk2(ev_[q][2] * rinv_, ev_[q][3] * rinv_);                    \
        uu_.w[2] = pk2(ev_[q][4] * rinv_, ev_[q][5] * rinv_);                    \
        uu_.w[3] = pk2(ev_[q][6] * rinv_, ev_[q][7] * rinv_);                    \
        bf16x8 af_ = uu_.v;                                                      \
        oacc0 = MFMA32(af_, lds_frag(&XT[cs + l31][q * 16 + hl * 8]), oacc0);    \
        oacc1 = MFMA32(af_, lds_frag(&XT[cs + 32 + l31][q * 16 + hl * 8]), oacc1); \
    }                                                                            \
} while (0)

__global__ __launch_bounds__(256, 2)
void gat_kernel(float* __restrict__ Htemp,
                const unsigned short* __restrict__ gwb,
                const float* __restrict__ waS, const float* __restrict__ waD,
                const float* __restrict__ gbias,
                const unsigned long long* __restrict__ masks,
                const float* __restrict__ sg, const float* __restrict__ sb) {
    __shared__ unsigned short Htb[64][132];        // 16896 B, residual + xh A-operand
    __shared__ double xbuf0[2176];                 // 17408 B, xhT buffer 0
    __shared__ double xbuf1[2176];                 // 17408 B, xhT buffer 1
    __shared__ float asrcF[4][64], adstF[4][64];   // 2048 B
    __shared__ float pr0[2][64], pr1[2][64];       // 1024 B (final-LN reduce)
    __shared__ unsigned long long mk[64];          // 512 B
    __shared__ unsigned long long mTT[64];         // 512 B (mask transposed: bit s of mTT[t])

    unsigned short (*xhT0)[68] = (unsigned short(*)[68])xbuf0;
    unsigned short (*xhT1)[68] = (unsigned short(*)[68])xbuf1;
    float (*part)[8][64]       = (float(*)[8][64])xbuf0;   // overlay, used pre-loop

    const int bp = blockIdx.x;
    const int b = bp >> 7, p = bp & 127;
    const int tid = threadIdx.x;
    const int lane = tid & 63, wv = tid >> 6;
    const int hl = lane >> 5, l31 = lane & 31;
    const int rs = (wv & 1) * 32;
    const int cs = (wv >> 1) * 64;

    {
        int c = tid >> 2, qq = tid & 3;
        const float* src = Htemp + ((long)(b * 64 + c) * 128 + p) * 128 + qq * 32;
#pragma unroll
        for (int k = 0; k < 8; k++) {
            float4 t4 = *(const float4*)(src + 4 * k);
            ushort4 u; u.x = f2bf(t4.x); u.y = f2bf(t4.y); u.z = f2bf(t4.z); u.w = f2bf(t4.w);
            *(ushort4*)&Htb[c][qq * 32 + 4 * k] = u;
        }
    }
    if (tid < 64) mk[tid] = masks[b * 64 + tid];
    __syncthreads();

    // ---- per-source asrc/adst partials (part overlays xhT0; consumed below) ----
    {
        int s = lane, q = wv;
        float acc[8];
#pragma unroll
        for (int m = 0; m < 8; m++) acc[m] = 0.f;
        const unsigned int* hp = (const unsigned int*)&Htb[s][q * 32];
#pragma unroll
        for (int d2 = 0; d2 < 16; d2++) {
            unsigned int u = hp[d2];
            float f0 = __uint_as_float(u << 16);
            float f1 = __uint_as_float(u & 0xffff0000u);
            int d = q * 32 + 2 * d2;
#pragma unroll
            for (int h = 0; h < 4; h++) {
                acc[2*h]   += f0 * waS[h * 128 + d] + f1 * waS[h * 128 + d + 1];
                acc[2*h+1] += f0 * waD[h * 128 + d] + f1 * waD[h * 128 + d + 1];
            }
        }
#pragma unroll
        for (int m = 0; m < 8; m++) part[q][m][s] = acc[m];
    }
    __syncthreads();
    for (int o = tid; o < 512; o += 256) {
        int h = o >> 7, rem = o & 127, which = rem >> 6, s = rem & 63;
        int m = h * 2 + which;
        float v = part[0][m][s] + part[1][m][s] + part[2][m][s] + part[3][m][s];
        if (which == 0) asrcF[h][s] = v; else adstF[h][s] = v;
    }
    // mask transpose: mTT[t] bit s = (mk[s] >> t) & 1
    if (tid < 64) {
        unsigned long long m = 0ull;
        for (int s = 0; s < 64; s++)
            m |= ((mk[s] >> tid) & 1ull) << s;
        mTT[tid] = m;
    }
    __syncthreads();   // asrcF/adstF/mTT ready; part region free for xhT0

    const unsigned long long mt = mTT[rs + l31];   // this lane's target mask row

    f32x16 oacc0, oacc1;
#pragma unroll
    for (int r = 0; r < 16; r++) { oacc0[r] = 0.f; oacc1[r] = 0.f; }

    // ---- pipelined head loop: 1 barrier/head ----
    XH_STAGE(0, xhT0);
    __syncthreads();
    PV_PHASE(0, xhT0, XH_STAGE(1, xhT1));
    __syncthreads();
    PV_PHASE(1, xhT1, XH_STAGE(2, xhT0));
    __syncthreads();
    PV_PHASE(2, xhT0, XH_STAGE(3, xhT1));
    __syncthreads();
    PV_PHASE(3, xhT1, (void)0);

    // ---- epilogue: mean over heads, +bias, +residual, final LN ----
    float gb0 = gbias[cs + l31], gb1 = gbias[cs + 32 + l31];
    float v0[16], v1[16];
#pragma unroll
    for (int r = 0; r < 16; r++) {
        int c = rs + rowmap(r, hl);
        v0[r] = oacc0[r] * 0.25f + gb0 + bf2f(Htb[c][cs + l31]);
        v1[r] = oacc1[r] * 0.25f + gb1 + bf2f(Htb[c][cs + 32 + l31]);
    }
#pragma unroll
    for (int r = 0; r < 16; r++) {
        float s = v0[r] + v1[r];
        float q = v0[r] * v0[r] + v1[r] * v1[r];
#pragma unroll
        for (int d = 1; d < 32; d <<= 1) { s += __shfl_xor(s, d); q += __shfl_xor(q, d); }
        if (l31 == 0) {
            int c = rs + rowmap(r, hl);
            pr0[wv >> 1][c] = s;
            pr1[wv >> 1][c] = q;
        }
    }
    __syncthreads();
    float sgv0 = sg[cs + l31], sbv0 = sb[cs + l31];
    float sgv1 = sg[cs + 32 + l31], sbv1 = sb[cs + 32 + l31];
#pragma unroll
    for (int r = 0; r < 16; r++) {
        int c = rs + rowmap(r, hl);
        float sum = pr0[0][c] + pr0[1][c];
        float sq  = pr1[0][c] + pr1[1][c];
        float mu = sum * 0.0078125f;
        float var = sq * 0.0078125f - mu * mu;
        float rsd = rsqrtf(fmaxf(var, 0.f) + 1e-5f);
        float* orow = Htemp + ((long)(b * 64 + c) * 128 + p) * 128;
        orow[cs + l31]      = (v0[r] - mu) * rsd * sgv0 + sbv0;
        orow[cs + 32 + l31] = (v1[r] - mu) * rsd * sgv1 + sbv1;
    }
}

// ---------------------------------------------------------------------------
extern "C" void kernel_launch(void* const* d_in, const int* in_sizes, int n_in,
                              void* d_out, int out_size, void* d_ws, size_t ws_size,
                              hipStream_t stream) {
    const float* Hin        = (const float*)d_in[0];
    const float* static_adj = (const float*)d_in[1];
    const float* attn_in_w  = (const float*)d_in[2];
    const float* attn_in_b  = (const float*)d_in[3];
    const float* attn_out_w = (const float*)d_in[4];
    const float* attn_out_b = (const float*)d_in[5];
    const float* ln1_g      = (const float*)d_in[6];
    const float* ln1_b      = (const float*)d_in[7];
    const float* ln2_g      = (const float*)d_in[8];
    const float* ln2_b      = (const float*)d_in[9];
    const float* ff1_w      = (const float*)d_in[10];
    const float* ff1_b      = (const float*)d_in[11];
    const float* ff2_w      = (const float*)d_in[12];
    const float* ff2_b      = (const float*)d_in[13];
    const float* tnorm_g    = (const float*)d_in[14];
    const float* tnorm_b    = (const float*)d_in[15];
    const float* q_w        = (const float*)d_in[16];
    const float* q_b        = (const float*)d_in[17];
    const float* k_w        = (const float*)d_in[18];
    const float* k_b        = (const float*)d_in[19];
    const float* gat_w      = (const float*)d_in[20];
    const float* gat_att_src= (const float*)d_in[21];
    const float* gat_att_dst= (const float*)d_in[22];
    const float* gat_bias   = (const float*)d_in[23];
    const float* snorm_g    = (const float*)d_in[24];
    const float* snorm_b    = (const float*)d_in[25];

    float* out = (float*)d_out;   // H_temp (then overwritten by final result)
    char* ws = (char*)d_ws;
    unsigned short* wb = (unsigned short*)ws;                 // 524288 B (bf16 weights)
    const unsigned short* wqkv_b = wb;
    const unsigned short* wout_b = wb + 49152;
    const unsigned short* w1_b   = wb + 65536;
    const unsigned short* w2_b   = wb + 131072;
    const unsigned short* gw_b   = wb + 196608;
    unsigned long long* masks = (unsigned long long*)(ws + 524288);   // 8192 B
    float* Hs  = (float*)(ws + 532480);                               // 524288 B
    float* waS = (float*)(ws + 1056768);                              // 2048 B
    float* waD = (float*)(ws + 1058816);                              // 2048 B

    hipLaunchKernelGGL(wconv_kernel, dim3(1024), dim3(256), 0, stream,
                       attn_in_w, attn_out_w, ff1_w, ff2_w, gat_w, wb);
    hipLaunchKernelGGL(wa_kernel, dim3(4), dim3(256), 0, stream,
                       gat_w, gat_att_src, gat_att_dst, waS, waD);
    hipLaunchKernelGGL(temporal_kernel, dim3(1024), dim3(256), 0, stream,
                       Hin, wqkv_b, attn_in_b, wout_b, attn_out_b,
                       ln1_g, ln1_b, ln2_g, ln2_b,
                       w1_b, ff1_b, w2_b, ff2_b, tnorm_g, tnorm_b, out, Hs);
    hipLaunchKernelGGL(graph_kernel, dim3(16), dim3(256), 0, stream,
                       Hs, q_w, q_b, k_w, k_b, static_adj, masks);
    hipLaunchKernelGGL(gat_kernel, dim3(2048), dim3(256), 0, stream,
                       out, gw_b, waS, waD, gat_bias,
                       masks, snorm_g, snorm_b);
}

// Round 7
// 537.552 us; speedup vs baseline: 1.0550x; 1.0550x over previous
//
#include <hip/hip_runtime.h>
#include <cstdint>

// B=16, C=64, Np=128, D=128, HT=4 (dh=32), HS=4, F=128, DK=64, TOPK=8

typedef __attribute__((ext_vector_type(8)))  short bf16x8;
typedef __attribute__((ext_vector_type(16))) float f32x16;
#define MFMA32(a, b, c) __builtin_amdgcn_mfma_f32_32x32x16_bf16((a), (b), (c), 0, 0, 0)

__device__ __forceinline__ unsigned short f2bf(float f) {
    unsigned int u = __float_as_uint(f);
    u += 0x7fffu + ((u >> 16) & 1u);
    return (unsigned short)(u >> 16);
}
__device__ __forceinline__ float bf2f(unsigned short u) {
    return __uint_as_float(((unsigned int)u) << 16);
}

__device__ __forceinline__ bf16x8 lds_frag(const unsigned short* p) {
    union { bf16x8 v; ushort4 h[2]; } u;
    u.h[0] = *(const ushort4*)p;
    u.h[1] = *(const ushort4*)(p + 4);
    return u.v;
}
__device__ __forceinline__ bf16x8 gfrag(const unsigned short* p) {
    union { bf16x8 v; uint4 u; } t;
    t.u = *(const uint4*)p;
    return t.v;
}

// C/D layout for 32x32x16: col = lane&31, row = (reg&3) + 8*(reg>>2) + 4*(lane>>5)
__device__ __forceinline__ int rowmap(int r, int hl) { return (r & 3) + 8 * (r >> 2) + 4 * hl; }

__device__ __forceinline__ unsigned int pk2(float lo, float hi) {
    return (unsigned int)f2bf(lo) | ((unsigned int)f2bf(hi) << 16);
}

// Build an MFMA A/B fragment (16-wide k-chunk) from a C-layout f32x16.
// Partner 4-groups fetched with v_permlane32_swap_b32 (lanes[0:31] <-> lanes[32:63]).
template<int B>
__device__ __forceinline__ bf16x8 pack_frag(const f32x16& p) {
    unsigned int a0 = pk2(p[B + 0], p[B + 1]);
    unsigned int a1 = pk2(p[B + 2], p[B + 3]);
    unsigned int b0 = pk2(p[B + 4], p[B + 5]);
    unsigned int b1 = pk2(p[B + 6], p[B + 7]);
    asm("v_permlane32_swap_b32 %0, %1" : "+v"(b0), "+v"(a0));
    asm("v_permlane32_swap_b32 %0, %1" : "+v"(b1), "+v"(a1));
    union { bf16x8 v; unsigned int w[4]; } u;
    u.w[0] = a0; u.w[1] = a1; u.w[2] = b0; u.w[3] = b1;
    return u.v;
}

// ---------------------------------------------------------------------------
// wconv (1024 blocks) + wa (4 blocks) merged: one launch fewer.
__global__ void prep_kernel(const float* __restrict__ wqkv, const float* __restrict__ wout,
                            const float* __restrict__ w1, const float* __restrict__ w2,
                            const float* __restrict__ gw,
                            const float* __restrict__ asw, const float* __restrict__ adw,
                            unsigned short* __restrict__ dst,
                            float* __restrict__ waS, float* __restrict__ waD) {
    if (blockIdx.x < 1024) {
        int i = blockIdx.x * 256 + threadIdx.x;   // 262144 total
        float v;
        if (i < 49152)       v = wqkv[i];
        else if (i < 65536)  v = wout[i - 49152];
        else if (i < 131072) v = w1[i - 65536];
        else if (i < 196608) v = w2[i - 131072];
        else                 v = gw[i - 196608];
        dst[i] = f2bf(v);
    } else {
        int t = (blockIdx.x - 1024) * 256 + threadIdx.x;   // 1024
        int h = t >> 8, d = (t >> 1) & 127, which = t & 1;
        const float* av = which ? adw : asw;
        float s = 0.f;
        for (int f = 0; f < 128; f++) s += av[h * 128 + f] * gw[(h * 128 + f) * 128 + d];
        (which ? waD : waS)[h * 128 + d] = s;
    }
}

// ---------------------------------------------------------------------------
// Fused temporal block (R5-verified at 243 us). BF16=1: final H_temp written
// as bf16 in gat's layout [b][p][c][d] (33.5 MB vs 67 MB f32; gat already
// consumed bf16-rounded values, so results are bit-identical).
#define QKV_STAGE(H, KBB, VTB) do {                                              \
    f32x16 accq, acck, accv;                                                     \
    _Pragma("unroll") for (int r = 0; r < 16; r++)                               \
        accq[r] = bqkv[(H) * 32 + rowmap(r, hl)];                                \
    float bk_ = bqkv[128 + (H) * 32 + l31];                                      \
    float bv_ = bqkv[256 + (H) * 32 + l31];                                      \
    _Pragma("unroll") for (int r = 0; r < 16; r++) { acck[r] = bk_; accv[r] = bv_; } \
    const unsigned short* wq_ = wqkv_b + ((H) * 32 + l31) * 128 + hl * 8;        \
    const unsigned short* wk_ = wqkv_b + (128 + (H) * 32 + l31) * 128 + hl * 8;  \
    const unsigned short* wv_ = wqkv_b + (256 + (H) * 32 + l31) * 128 + hl * 8;  \
    _Pragma("unroll") for (int k0 = 0; k0 < 128; k0 += 16) {                     \
        bf16x8 a_ = lds_frag(&RA[myrow][k0 + hl * 8]);                           \
        accq = MFMA32(gfrag(wq_ + k0), a_, accq);  /* Q^T: rows=dh, cols=toks */ \
        acck = MFMA32(a_, gfrag(wk_ + k0), acck);                                \
        accv = MFMA32(a_, gfrag(wv_ + k0), accv);                                \
    }                                                                            \
    _Pragma("unroll") for (int r = 0; r < 16; r++) {                             \
        int tok_ = wv * 32 + rowmap(r, hl);                                      \
        KBB[tok_][l31] = f2bf(acck[r]);                                          \
        VTB[l31][tok_] = f2bf(accv[r]);                                          \
    }                                                                            \
    qf0_ = pack_frag<0>(accq);                                                   \
    qf1_ = pack_frag<8>(accq);                                                   \
} while (0)

#define ATTN_PHASE(H, KBB, VTB, NEXTQKV) do {                                    \
    f32x16 sacc[4];                                                              \
    _Pragma("unroll") for (int t = 0; t < 4; t++)                                \
    _Pragma("unroll") for (int r = 0; r < 16; r++) sacc[t][r] = 0.f;             \
    _Pragma("unroll") for (int t = 0; t < 4; t++) {                              \
        bf16x8 ka0 = lds_frag(&KBB[t * 32 + l31][hl * 8]);                       \
        sacc[t] = MFMA32(ka0, qf0_, sacc[t]);                                    \
        bf16x8 ka1 = lds_frag(&KBB[t * 32 + l31][16 + hl * 8]);                  \
        sacc[t] = MFMA32(ka1, qf1_, sacc[t]);                                    \
    }                                                                            \
    NEXTQKV;                                                                     \
    const float scale_ = 0.17677669529663687f;   /* 1/sqrt(32) */                \
    float m0 = -1e30f;                                                           \
    _Pragma("unroll") for (int t = 0; t < 4; t++)                                \
    _Pragma("unroll") for (int r = 0; r < 16; r++) m0 = fmaxf(m0, sacc[t][r]);   \
    m0 = fmaxf(m0, __shfl_xor(m0, 32));                                          \
    float ssum = 0.f;                                                            \
    _Pragma("unroll") for (int t = 0; t < 4; t++)                                \
    _Pragma("unroll") for (int r = 0; r < 16; r++) {                             \
        float e_ = __expf(scale_ * (sacc[t][r] - m0));                           \
        sacc[t][r] = e_; ssum += e_;                                             \
    }                                                                            \
    ssum += __shfl_xor(ssum, 32);                                                \
    float rinv_ = 1.f / ssum;                                                    \
    _Pragma("unroll") for (int t = 0; t < 4; t++)                                \
    _Pragma("unroll") for (int r = 0; r < 16; r++) sacc[t][r] *= rinv_;          \
    f32x16 oacc;                                                                 \
    _Pragma("unroll") for (int r = 0; r < 16; r++) oacc[r] = 0.f;                \
    _Pragma("unroll") for (int t = 0; t < 4; t++) {                              \
        bf16x8 pf0 = pack_frag<0>(sacc[t]);                                      \
        bf16x8 v0_ = lds_frag(&VTB[l31][t * 32 + hl * 8]);                       \
        oacc = MFMA32(pf0, v0_, oacc);                                           \
        bf16x8 pf1 = pack_frag<8>(sacc[t]);                                      \
        bf16x8 v1_ = lds_frag(&VTB[l31][t * 32 + 16 + hl * 8]);                  \
        oacc = MFMA32(pf1, v1_, oacc);                                           \
    }                                                                            \
    _Pragma("unroll") for (int j = 0; j < 8; j++)                                \
        opk[H][j] = pk2(oacc[2*j], oacc[2*j+1]);                                 \
} while (0)

template<int BF16>
__global__ __launch_bounds__(256, 2)
void temporal_kernel(const float* __restrict__ Hin,
                     const unsigned short* __restrict__ wqkv_b, const float* __restrict__ bqkv,
                     const unsigned short* __restrict__ wout_b, const float* __restrict__ bout,
                     const float* __restrict__ g1, const float* __restrict__ b1,
                     const float* __restrict__ g2, const float* __restrict__ b2,
                     const unsigned short* __restrict__ w1_b, const float* __restrict__ bf1,
                     const unsigned short* __restrict__ w2_b, const float* __restrict__ bf2,
                     const float* __restrict__ tg, const float* __restrict__ tb,
                     float* __restrict__ Htemp, float* __restrict__ Hs,
                     unsigned short* __restrict__ hbt) {
    // Region A (33792 B): hb (LN1 out) -> O (attn out) -> h2b (LN2 out). Wave-private rows.
    __shared__ unsigned short RA[128][132];
    // Region B (35328 B): attn dbuf {kb0,vT0,kb1,vT1} -> ffn {rscr | hsred}
    __shared__ double RBd[4416];
    unsigned short (*kb0)[36]  = (unsigned short(*)[36])RBd;                       // [tok][dh]
    unsigned short (*vT0)[132] = (unsigned short(*)[132])((char*)RBd + 9216);      // [d][tok]
    unsigned short (*kb1)[36]  = (unsigned short(*)[36])((char*)RBd + 17664);
    unsigned short (*vT1)[132] = (unsigned short(*)[132])((char*)RBd + 26880);
    unsigned short (*rscr)[32][36] = (unsigned short(*)[32][36])RBd;               // [0..9216) = kb0 region
    float (*hsred)[128] = (float(*)[128])((char*)RBd + 9216);                      // [9216..11264) = vT0 region

    const int n = blockIdx.x;
    const int tid = threadIdx.x;
    const int lane = tid & 63;
    const int wv = tid >> 6;
    const int hl = lane >> 5;
    const int l31 = lane & 31;
    const int myrow = wv * 32 + l31;

    // ---- LN1 (wave-private rows: tid>>1 maps wave w to rows w*32..w*32+31) ----
    {
        int row = tid >> 1, hf = tid & 1;
        const float* src = Hin + ((long)n * 128 + row) * 128 + hf * 64;
        float xv[64];
        float s = 0.f, qs = 0.f;
#pragma unroll
        for (int i = 0; i < 64; i += 4) {
            float4 t = *(const float4*)(src + i);
            xv[i] = t.x; xv[i+1] = t.y; xv[i+2] = t.z; xv[i+3] = t.w;
        }
#pragma unroll
        for (int i = 0; i < 64; i++) { s += xv[i]; qs += xv[i] * xv[i]; }
        s += __shfl_xor(s, 1); qs += __shfl_xor(qs, 1);
        float mu = s * 0.0078125f;
        float rs = rsqrtf(fmaxf(qs * 0.0078125f - mu * mu, 0.f) + 1e-5f);
#pragma unroll
        for (int i = 0; i < 64; i++) {
            int d = hf * 64 + i;
            RA[row][d] = f2bf((xv[i] - mu) * rs * g1[d] + b1[d]);
        }
    }
    // no barrier: RA rows are wave-private for QKV A-reads

    unsigned int opk[4][8];   // O, bf16-packed, per head (all indices literal)
    bf16x8 qf0_, qf1_;        // current head's Q fragments

    // ---- pipelined head loop: 1 barrier/head; QKV(h+1) overlaps phase h ----
    QKV_STAGE(0, kb0, vT0);
    __syncthreads();                                   // kb0/vT0 cross-wave
    ATTN_PHASE(0, kb0, vT0, QKV_STAGE(1, kb1, vT1));
    __syncthreads();                                   // kb1/vT1 ready; kb0/vT0 reads done
    ATTN_PHASE(1, kb1, vT1, QKV_STAGE(2, kb0, vT0));
    __syncthreads();
    ATTN_PHASE(2, kb0, vT0, QKV_STAGE(3, kb1, vT1));
    __syncthreads();
    ATTN_PHASE(3, kb1, vT1, (void)0);
    // no barrier: remainder touches only wave-private RA rows + rscr[wv] (kb0
    // region, disjoint from the kb1/vT1 still being read by slower waves).

    // ---- O (packed regs) -> RA (hb dead; wave-private rows) ----
#pragma unroll
    for (int h = 0; h < 4; h++)
#pragma unroll
        for (int j = 0; j < 8; j++) {
            int tok0 = wv * 32 + rowmap(2*j,     hl);
            int tok1 = wv * 32 + rowmap(2*j + 1, hl);
            RA[tok0][h * 32 + l31] = (unsigned short)(opk[h][j] & 0xffffu);
            RA[tok1][h * 32 + l31] = (unsigned short)(opk[h][j] >> 16);
        }

    // ---- x = x0 + bout + O @ Wout^T ----
    f32x16 acc[4];
#pragma unroll
    for (int t = 0; t < 4; t++) {
        float bo = bout[t * 32 + l31];
#pragma unroll
        for (int r = 0; r < 16; r++) {
            int tok = wv * 32 + rowmap(r, hl);
            acc[t][r] = Hin[((long)n * 128 + tok) * 128 + t * 32 + l31] + bo;
        }
    }
#pragma unroll
    for (int k0 = 0; k0 < 128; k0 += 16) {
        bf16x8 a = lds_frag(&RA[myrow][k0 + hl * 8]);
#pragma unroll
        for (int t = 0; t < 4; t++) {
            bf16x8 b = gfrag(wout_b + (t * 32 + l31) * 128 + k0 + hl * 8);
            acc[t] = MFMA32(a, b, acc[t]);
        }
    }

    // ---- LN2 -> RA (h2b; O dead, wave-private rows) ----
#pragma unroll
    for (int r = 0; r < 16; r++) {
        float s = acc[0][r] + acc[1][r] + acc[2][r] + acc[3][r];
#pragma unroll
        for (int d = 1; d < 32; d <<= 1) s += __shfl_xor(s, d);
        float mu = s * 0.0078125f;
        float q = 0.f;
#pragma unroll
        for (int t = 0; t < 4; t++) { float dv = acc[t][r] - mu; q += dv * dv; }
#pragma unroll
        for (int d = 1; d < 32; d <<= 1) q += __shfl_xor(q, d);
        float rs = rsqrtf(q * 0.0078125f + 1e-5f);
        int row = wv * 32 + rowmap(r, hl);
#pragma unroll
        for (int t = 0; t < 4; t++) {
            int col = t * 32 + l31;
            RA[row][col] = f2bf((acc[t][r] - mu) * rs * g2[col] + b2[col]);
        }
    }

    // acc := x + bf2 in place
#pragma unroll
    for (int t = 0; t < 4; t++) {
        float bv = bf2[t * 32 + l31];
#pragma unroll
        for (int r = 0; r < 16; r++) acc[t][r] += bv;
    }

    // ---- FFN in 4 K-chunks of 128; parallel racc tiles, relu via per-wave rscr ----
    for (int j = 0; j < 4; j++) {
        f32x16 racc[4];
#pragma unroll
        for (int t = 0; t < 4; t++) {
            float bv = bf1[j * 128 + t * 32 + l31];
#pragma unroll
            for (int r = 0; r < 16; r++) racc[t][r] = bv;
        }
#pragma unroll
        for (int k0 = 0; k0 < 128; k0 += 16) {
            bf16x8 a = lds_frag(&RA[myrow][k0 + hl * 8]);   // h2b
#pragma unroll
            for (int t = 0; t < 4; t++) {
                bf16x8 b = gfrag(w1_b + (j * 128 + t * 32 + l31) * 128 + k0 + hl * 8);
                racc[t] = MFMA32(a, b, racc[t]);
            }
        }
#pragma unroll
        for (int t = 0; t < 4; t++) {
#pragma unroll
            for (int r = 0; r < 16; r++)
                rscr[wv][rowmap(r, hl)][l31] = f2bf(fmaxf(racc[t][r], 0.f));
#pragma unroll
            for (int kk = 0; kk < 32; kk += 16) {
                bf16x8 a = lds_frag(&rscr[wv][l31][kk + hl * 8]);
#pragma unroll
                for (int tp = 0; tp < 4; tp++) {
                    bf16x8 b = gfrag(w2_b + (tp * 32 + l31) * 512 + j * 128 + t * 32 + kk + hl * 8);
                    acc[tp] = MFMA32(a, b, acc[tp]);
                }
            }
        }
    }

    // ---- H_temp = LN(x0 + x', tg, tb); accumulate Hs column sums ----
#pragma unroll
    for (int t = 0; t < 4; t++)
#pragma unroll
        for (int r = 0; r < 16; r++) {
            int tok = wv * 32 + rowmap(r, hl);
            acc[t][r] += Hin[((long)n * 128 + tok) * 128 + t * 32 + l31];
        }
    const int bb = n >> 6, cc = n & 63;   // n = b*64 + c
    float* outf = Htemp + (long)n * 16384;
    float cs0 = 0.f, cs1 = 0.f, cs2 = 0.f, cs3 = 0.f;
#pragma unroll
    for (int r = 0; r < 16; r++) {
        float s = acc[0][r] + acc[1][r] + acc[2][r] + acc[3][r];
#pragma unroll
        for (int d = 1; d < 32; d <<= 1) s += __shfl_xor(s, d);
        float mu = s * 0.0078125f;
        float q = 0.f;
#pragma unroll
        for (int t = 0; t < 4; t++) { float dv = acc[t][r] - mu; q += dv * dv; }
#pragma unroll
        for (int d = 1; d < 32; d <<= 1) q += __shfl_xor(q, d);
        float rs = rsqrtf(q * 0.0078125f + 1e-5f);
        int tok = wv * 32 + rowmap(r, hl);
        float v0 = (acc[0][r] - mu) * rs * tg[0 * 32 + l31] + tb[0 * 32 + l31];
        float v1 = (acc[1][r] - mu) * rs * tg[1 * 32 + l31] + tb[1 * 32 + l31];
        float v2 = (acc[2][r] - mu) * rs * tg[2 * 32 + l31] + tb[2 * 32 + l31];
        float v3 = (acc[3][r] - mu) * rs * tg[3 * 32 + l31] + tb[3 * 32 + l31];
        cs0 += v0; cs1 += v1; cs2 += v2; cs3 += v3;
        if constexpr (BF16) {
            unsigned short* ob = hbt + ((long)(bb * 128 + tok) * 64 + cc) * 128 + l31;
            ob[0]  = f2bf(v0);
            ob[32] = f2bf(v1);
            ob[64] = f2bf(v2);
            ob[96] = f2bf(v3);
        } else {
            outf[tok * 128 + 0 * 32 + l31] = v0;
            outf[tok * 128 + 1 * 32 + l31] = v1;
            outf[tok * 128 + 2 * 32 + l31] = v2;
            outf[tok * 128 + 3 * 32 + l31] = v3;
        }
    }
    // per-wave: sum own 16 toks + partner-half 16 toks = wave's 32 toks
    cs0 += __shfl_xor(cs0, 32); cs1 += __shfl_xor(cs1, 32);
    cs2 += __shfl_xor(cs2, 32); cs3 += __shfl_xor(cs3, 32);
    if (hl == 0) {
        hsred[wv][0 * 32 + l31] = cs0;
        hsred[wv][1 * 32 + l31] = cs1;
        hsred[wv][2 * 32 + l31] = cs2;
        hsred[wv][3 * 32 + l31] = cs3;
    }
    __syncthreads();
    if (tid < 128)
        Hs[(long)n * 128 + tid] =
            (hsred[0][tid] + hsred[1][tid] + hsred[2][tid] + hsred[3][tid]) * 0.0078125f;
}

// ---------------------------------------------------------------------------
__global__ __launch_bounds__(256)
void graph_kernel(const float* __restrict__ Hs,
                  const float* __restrict__ qw, const float* __restrict__ qb,
                  const float* __restrict__ kw, const float* __restrict__ kb,
                  const float* __restrict__ adj, unsigned long long* __restrict__ masks) {
    __shared__ float q2l[64][65];
    __shared__ float k2l[64][65];
    __shared__ float am[64][65];
    int b = blockIdx.x;
    int tid = threadIdx.x;
    {
        int r = tid & 127, jh = tid >> 7;
        int row = r & 63;
        const float* wmat = (r < 64) ? qw : kw;
        const float* bvec = (r < 64) ? qb : kb;
        const float* src = Hs + (long)(b * 64 + row) * 128;
        for (int jj = 0; jj < 32; jj++) {
            int j = jh * 32 + jj;
            const float* wrow = wmat + (long)j * 128;
            float s0 = 0.f, s1 = 0.f, s2 = 0.f, s3 = 0.f;
#pragma unroll
            for (int d = 0; d < 128; d += 4) {
                s0 += src[d] * wrow[d];     s1 += src[d+1] * wrow[d+1];
                s2 += src[d+2] * wrow[d+2]; s3 += src[d+3] * wrow[d+3];
            }
            float val = ((s0 + s1) + (s2 + s3)) + bvec[j];
            if (r < 64) q2l[row][j] = val; else k2l[row][j] = val;
        }
    }
    __syncthreads();
    {
        int c = tid & 63, eq = tid >> 6;
        for (int ee = 0; ee < 16; ee++) {
            int e = eq * 16 + ee;
            float s0 = 0.f, s1 = 0.f, s2 = 0.f, s3 = 0.f;
#pragma unroll
            for (int j = 0; j < 64; j += 4) {
                s0 += q2l[c][j]   * k2l[e][j];
                s1 += q2l[c][j+1] * k2l[e][j+1];
                s2 += q2l[c][j+2] * k2l[e][j+2];
                s3 += q2l[c][j+3] * k2l[e][j+3];
            }
            float sim = ((s0 + s1) + (s2 + s3)) * 0.125f;
            am[c][e] = tanhf(sim) + adj[c * 64 + e];
        }
    }
    __syncthreads();
    if (tid < 64) {
        int c = tid;
        unsigned long long sel = 0ull;
        for (int it = 0; it < 8; it++) {
            float best = -1e38f; int bi = 0;
            for (int e = 0; e < 64; e++) {
                float v = am[c][e];
                bool ok = (((sel >> e) & 1ull) == 0ull) && (v > best);
                best = ok ? v : best;
                bi = ok ? e : bi;
            }
            sel |= (1ull << bi);
        }
        sel &= ~(1ull << c);
        for (int e = 0; e < 64; e++)
            if (am[c][e] == 0.f) sel &= ~(1ull << e);
        masks[b * 64 + c] = sel;
    }
}

// ---------------------------------------------------------------------------
// GAT + final LN — R5-verified structure. BF16=1: Htb loaded directly from
// the bf16 transposed intermediate (contiguous 16 KB/block, no conversion).
template<int BF16>
__global__ __launch_bounds__(256, 2)
void gat_kernel(float* __restrict__ Htemp,
                const unsigned short* __restrict__ hbt,
                const unsigned short* __restrict__ gwb,
                const float* __restrict__ waS, const float* __restrict__ waD,
                const float* __restrict__ gbias,
                const unsigned long long* __restrict__ masks,
                const float* __restrict__ sg, const float* __restrict__ sb) {
    __shared__ unsigned short Htb[64][132];
    __shared__ double ovl_d[3264];
    __shared__ float asrcF[4][64], adstF[4][64];
    __shared__ float pmax[4][64], psum[4][64];
    __shared__ unsigned long long mk[64];

    unsigned short (*xhT)[68]  = (unsigned short(*)[68])ovl_d;
    unsigned short (*attT)[68] = (unsigned short(*)[68])((char*)ovl_d + 17408);
    float (*part)[8][64]       = (float(*)[8][64])ovl_d;

    const int bp = blockIdx.x;
    const int b = bp >> 7, p = bp & 127;
    const int tid = threadIdx.x;
    const int lane = tid & 63, wv = tid >> 6;
    const int hl = lane >> 5, l31 = lane & 31;
    const int rs = (wv & 1) * 32;
    const int cs = (wv >> 1) * 64;

    if constexpr (BF16) {
        int c = tid >> 2, qq = tid & 3;
        const unsigned short* src = hbt + ((long)(b * 128 + p) * 64 + c) * 128 + qq * 32;
#pragma unroll
        for (int m = 0; m < 8; m++)
            *(ushort4*)&Htb[c][qq * 32 + 4 * m] = *(const ushort4*)(src + 4 * m);
    } else {
        int c = tid >> 2, qq = tid & 3;
        const float* src = Htemp + ((long)(b * 64 + c) * 128 + p) * 128 + qq * 32;
#pragma unroll
        for (int k = 0; k < 8; k++) {
            float4 t4 = *(const float4*)(src + 4 * k);
            ushort4 u; u.x = f2bf(t4.x); u.y = f2bf(t4.y); u.z = f2bf(t4.z); u.w = f2bf(t4.w);
            *(ushort4*)&Htb[c][qq * 32 + 4 * k] = u;
        }
    }
    if (tid < 64) mk[tid] = masks[b * 64 + tid];
    __syncthreads();

    {
        int s = lane, q = wv;
        float acc[8];
#pragma unroll
        for (int m = 0; m < 8; m++) acc[m] = 0.f;
        const unsigned int* hp = (const unsigned int*)&Htb[s][q * 32];
#pragma unroll
        for (int d2 = 0; d2 < 16; d2++) {
            unsigned int u = hp[d2];
            float f0 = __uint_as_float(u << 16);
            float f1 = __uint_as_float(u & 0xffff0000u);
            int d = q * 32 + 2 * d2;
#pragma unroll
            for (int h = 0; h < 4; h++) {
                acc[2*h]   += f0 * waS[h * 128 + d] + f1 * waS[h * 128 + d + 1];
                acc[2*h+1] += f0 * waD[h * 128 + d] + f1 * waD[h * 128 + d + 1];
            }
        }
#pragma unroll
        for (int m = 0; m < 8; m++) part[q][m][s] = acc[m];
    }
    __syncthreads();
    for (int o = tid; o < 512; o += 256) {
        int h = o >> 7, rem = o & 127, which = rem >> 6, s = rem & 63;
        int m = h * 2 + which;
        float v = part[0][m][s] + part[1][m][s] + part[2][m][s] + part[3][m][s];
        if (which == 0) asrcF[h][s] = v; else adstF[h][s] = v;
    }
    __syncthreads();

    f32x16 oacc0, oacc1;
#pragma unroll
    for (int r = 0; r < 16; r++) { oacc0[r] = 0.f; oacc1[r] = 0.f; }

    for (int h = 0; h < 4; h++) {
        f32x16 a0, a1;
#pragma unroll
        for (int r = 0; r < 16; r++) { a0[r] = 0.f; a1[r] = 0.f; }
        const unsigned short* gwh = gwb + h * 16384;
#pragma unroll
        for (int k0 = 0; k0 < 128; k0 += 16) {
            bf16x8 af = lds_frag(&Htb[rs + l31][k0 + hl * 8]);
            bf16x8 b0 = gfrag(gwh + (cs + l31) * 128 + k0 + hl * 8);
            bf16x8 b1 = gfrag(gwh + (cs + 32 + l31) * 128 + k0 + hl * 8);
            a0 = MFMA32(af, b0, a0);
            a1 = MFMA32(af, b1, a1);
        }
#pragma unroll
        for (int g = 0; g < 4; g++) {
            ushort4 u0, u1;
            u0.x = f2bf(a0[4*g]);   u0.y = f2bf(a0[4*g+1]);
            u0.z = f2bf(a0[4*g+2]); u0.w = f2bf(a0[4*g+3]);
            u1.x = f2bf(a1[4*g]);   u1.y = f2bf(a1[4*g+1]);
            u1.z = f2bf(a1[4*g+2]); u1.w = f2bf(a1[4*g+3]);
            int so = rs + 4 * hl + 8 * g;
            *(ushort4*)&xhT[cs + l31][so]      = u0;
            *(ushort4*)&xhT[cs + 32 + l31][so] = u1;
        }
        __syncthreads();

        {
            int t = lane;
            float adv = adstF[h][t];
            float ev[16];
            float mx = -1e30f;
#pragma unroll
            for (int i = 0; i < 16; i++) {
                int s = wv * 16 + i;
                float e = asrcF[h][s] + adv;
                e = (e > 0.f) ? e : 0.2f * e;
                ev[i] = e;
                if ((mk[s] >> t) & 1ull) mx = fmaxf(mx, e);
            }
            pmax[wv][t] = mx;
            __syncthreads();
            float M = fmaxf(fmaxf(pmax[0][t], pmax[1][t]), fmaxf(pmax[2][t], pmax[3][t]));
            float sm = 0.f;
#pragma unroll
            for (int i = 0; i < 16; i++) {
                int s = wv * 16 + i;
                float w = ((mk[s] >> t) & 1ull) ? __expf(ev[i] - M) : 0.f;
                ev[i] = w; sm += w;
            }
            psum[wv][t] = sm;
            __syncthreads();
            float S = psum[0][t] + psum[1][t] + psum[2][t] + psum[3][t];
            float rinv = (S > 0.f) ? 1.f / S : 0.f;
#pragma unroll
            for (int g = 0; g < 4; g++) {
                ushort4 u;
                u.x = f2bf(ev[4*g]   * rinv); u.y = f2bf(ev[4*g+1] * rinv);
                u.z = f2bf(ev[4*g+2] * rinv); u.w = f2bf(ev[4*g+3] * rinv);
                *(ushort4*)&attT[t][wv * 16 + 4 * g] = u;
            }
        }
        __syncthreads();

#pragma unroll
        for (int k0 = 0; k0 < 64; k0 += 16) {
            bf16x8 af = lds_frag(&attT[rs + l31][k0 + hl * 8]);
            bf16x8 b0 = lds_frag(&xhT[cs + l31][k0 + hl * 8]);
            bf16x8 b1 = lds_frag(&xhT[cs + 32 + l31][k0 + hl * 8]);
            oacc0 = MFMA32(af, b0, oacc0);
            oacc1 = MFMA32(af, b1, oacc1);
        }
        __syncthreads();
    }

    float gb0 = gbias[cs + l31], gb1 = gbias[cs + 32 + l31];
    float v0[16], v1[16];
#pragma unroll
    for (int r = 0; r < 16; r++) {
        int c = rs + rowmap(r, hl);
        v0[r] = oacc0[r] * 0.25f + gb0 + bf2f(Htb[c][cs + l31]);
        v1[r] = oacc1[r] * 0.25f + gb1 + bf2f(Htb[c][cs + 32 + l31]);
    }
#pragma unroll
    for (int r = 0; r < 16; r++) {
        float s = v0[r] + v1[r];
        float q = v0[r] * v0[r] + v1[r] * v1[r];
#pragma unroll
        for (int d = 1; d < 32; d <<= 1) { s += __shfl_xor(s, d); q += __shfl_xor(q, d); }
        if (l31 == 0) {
            int c = rs + rowmap(r, hl);
            pmax[wv >> 1][c] = s;
            psum[wv >> 1][c] = q;
        }
    }
    __syncthreads();
    float sgv0 = sg[cs + l31], sbv0 = sb[cs + l31];
    float sgv1 = sg[cs + 32 + l31], sbv1 = sb[cs + 32 + l31];
#pragma unroll
    for (int r = 0; r < 16; r++) {
        int c = rs + rowmap(r, hl);
        float sum = pmax[0][c] + pmax[1][c];
        float sq  = psum[0][c] + psum[1][c];
        float mu = sum * 0.0078125f;
        float var = sq * 0.0078125f - mu * mu;
        float rsd = rsqrtf(fmaxf(var, 0.f) + 1e-5f);
        float* orow = Htemp + ((long)(b * 64 + c) * 128 + p) * 128;
        orow[cs + l31]      = (v0[r] - mu) * rsd * sgv0 + sbv0;
        orow[cs + 32 + l31] = (v1[r] - mu) * rsd * sgv1 + sbv1;
    }
}

// ---------------------------------------------------------------------------
extern "C" void kernel_launch(void* const* d_in, const int* in_sizes, int n_in,
                              void* d_out, int out_size, void* d_ws, size_t ws_size,
                              hipStream_t stream) {
    const float* Hin        = (const float*)d_in[0];
    const float* static_adj = (const float*)d_in[1];
    const float* attn_in_w  = (const float*)d_in[2];
    const float* attn_in_b  = (const float*)d_in[3];
    const float* attn_out_w = (const float*)d_in[4];
    const float* attn_out_b = (const float*)d_in[5];
    const float* ln1_g      = (const float*)d_in[6];
    const float* ln1_b      = (const float*)d_in[7];
    const float* ln2_g      = (const float*)d_in[8];
    const float* ln2_b      = (const float*)d_in[9];
    const float* ff1_w      = (const float*)d_in[10];
    const float* ff1_b      = (const float*)d_in[11];
    const float* ff2_w      = (const float*)d_in[12];
    const float* ff2_b      = (const float*)d_in[13];
    const float* tnorm_g    = (const float*)d_in[14];
    const float* tnorm_b    = (const float*)d_in[15];
    const float* q_w        = (const float*)d_in[16];
    const float* q_b        = (const float*)d_in[17];
    const float* k_w        = (const float*)d_in[18];
    const float* k_b        = (const float*)d_in[19];
    const float* gat_w      = (const float*)d_in[20];
    const float* gat_att_src= (const float*)d_in[21];
    const float* gat_att_dst= (const float*)d_in[22];
    const float* gat_bias   = (const float*)d_in[23];
    const float* snorm_g    = (const float*)d_in[24];
    const float* snorm_b    = (const float*)d_in[25];

    float* out = (float*)d_out;   // final result (gat writes all of it)
    char* ws = (char*)d_ws;
    unsigned short* wb = (unsigned short*)ws;                 // 524288 B (bf16 weights)
    const unsigned short* wqkv_b = wb;
    const unsigned short* wout_b = wb + 49152;
    const unsigned short* w1_b   = wb + 65536;
    const unsigned short* w2_b   = wb + 131072;
    const unsigned short* gw_b   = wb + 196608;
    unsigned long long* masks = (unsigned long long*)(ws + 524288);   // 8192 B
    float* Hs  = (float*)(ws + 532480);                               // 524288 B
    float* waS = (float*)(ws + 1056768);                              // 2048 B
    float* waD = (float*)(ws + 1058816);                              // 2048 B
    unsigned short* hbt = (unsigned short*)(ws + 1060864);            // 33554432 B (bf16 H_temp, [b][p][c][d])
    const bool big_ws = ws_size >= (size_t)(1060864 + 33554432);

    hipLaunchKernelGGL(prep_kernel, dim3(1028), dim3(256), 0, stream,
                       attn_in_w, attn_out_w, ff1_w, ff2_w, gat_w,
                       gat_att_src, gat_att_dst, wb, waS, waD);
    if (big_ws) {
        hipLaunchKernelGGL((temporal_kernel<1>), dim3(1024), dim3(256), 0, stream,
                           Hin, wqkv_b, attn_in_b, wout_b, attn_out_b,
                           ln1_g, ln1_b, ln2_g, ln2_b,
                           w1_b, ff1_b, w2_b, ff2_b, tnorm_g, tnorm_b, out, Hs, hbt);
        hipLaunchKernelGGL(graph_kernel, dim3(16), dim3(256), 0, stream,
                           Hs, q_w, q_b, k_w, k_b, static_adj, masks);
        hipLaunchKernelGGL((gat_kernel<1>), dim3(2048), dim3(256), 0, stream,
                           out, hbt, gw_b, waS, waD, gat_bias,
                           masks, snorm_g, snorm_b);
    } else {
        hipLaunchKernelGGL((temporal_kernel<0>), dim3(1024), dim3(256), 0, stream,
                           Hin, wqkv_b, attn_in_b, wout_b, attn_out_b,
                           ln1_g, ln1_b, ln2_g, ln2_b,
                           w1_b, ff1_b, w2_b, ff2_b, tnorm_g, tnorm_b, out, Hs, hbt);
        hipLaunchKernelGGL(graph_kernel, dim3(16), dim3(256), 0, stream,
                           Hs, q_w, q_b, k_w, k_b, static_adj, masks);
        hipLaunchKernelGGL((gat_kernel<0>), dim3(2048), dim3(256), 0, stream,
                           out, hbt, gw_b, waS, waD, gat_bias,
                           masks, snorm_g, snorm_b);
    }
}

// Round 8
// 532.121 us; speedup vs baseline: 1.0658x; 1.0102x over previous
//
#include <hip/hip_runtime.h>
#include <cstdint>

// B=16, C=64, Np=128, D=128, HT=4 (dh=32), HS=4, F=128, DK=64, TOPK=8

typedef __attribute__((ext_vector_type(8)))  short bf16x8;
typedef __attribute__((ext_vector_type(16))) float f32x16;
#define MFMA32(a, b, c) __builtin_amdgcn_mfma_f32_32x32x16_bf16((a), (b), (c), 0, 0, 0)

__device__ __forceinline__ unsigned short f2bf(float f) {
    unsigned int u = __float_as_uint(f);
    u += 0x7fffu + ((u >> 16) & 1u);
    return (unsigned short)(u >> 16);
}
__device__ __forceinline__ float bf2f(unsigned short u) {
    return __uint_as_float(((unsigned int)u) << 16);
}

__device__ __forceinline__ bf16x8 lds_frag(const unsigned short* p) {
    union { bf16x8 v; ushort4 h[2]; } u;
    u.h[0] = *(const ushort4*)p;
    u.h[1] = *(const ushort4*)(p + 4);
    return u.v;
}
__device__ __forceinline__ bf16x8 gfrag(const unsigned short* p) {
    union { bf16x8 v; uint4 u; } t;
    t.u = *(const uint4*)p;
    return t.v;
}

// C/D layout for 32x32x16: col = lane&31, row = (reg&3) + 8*(reg>>2) + 4*(lane>>5)
__device__ __forceinline__ int rowmap(int r, int hl) { return (r & 3) + 8 * (r >> 2) + 4 * hl; }

__device__ __forceinline__ unsigned int pk2(float lo, float hi) {
    return (unsigned int)f2bf(lo) | ((unsigned int)f2bf(hi) << 16);
}

// Build an MFMA A/B fragment (16-wide k-chunk) from a C-layout f32x16.
// Partner 4-groups fetched with v_permlane32_swap_b32 (lanes[0:31] <-> lanes[32:63]).
template<int B>
__device__ __forceinline__ bf16x8 pack_frag(const f32x16& p) {
    unsigned int a0 = pk2(p[B + 0], p[B + 1]);
    unsigned int a1 = pk2(p[B + 2], p[B + 3]);
    unsigned int b0 = pk2(p[B + 4], p[B + 5]);
    unsigned int b1 = pk2(p[B + 6], p[B + 7]);
    asm("v_permlane32_swap_b32 %0, %1" : "+v"(b0), "+v"(a0));
    asm("v_permlane32_swap_b32 %0, %1" : "+v"(b1), "+v"(a1));
    union { bf16x8 v; unsigned int w[4]; } u;
    u.w[0] = a0; u.w[1] = a1; u.w[2] = b0; u.w[3] = b1;
    return u.v;
}

// ---------------------------------------------------------------------------
// wconv (1024 blocks) + wa (4 blocks) merged: one launch fewer.
__global__ void prep_kernel(const float* __restrict__ wqkv, const float* __restrict__ wout,
                            const float* __restrict__ w1, const float* __restrict__ w2,
                            const float* __restrict__ gw,
                            const float* __restrict__ asw, const float* __restrict__ adw,
                            unsigned short* __restrict__ dst,
                            float* __restrict__ waS, float* __restrict__ waD) {
    if (blockIdx.x < 1024) {
        int i = blockIdx.x * 256 + threadIdx.x;   // 262144 total
        float v;
        if (i < 49152)       v = wqkv[i];
        else if (i < 65536)  v = wout[i - 49152];
        else if (i < 131072) v = w1[i - 65536];
        else if (i < 196608) v = w2[i - 131072];
        else                 v = gw[i - 196608];
        dst[i] = f2bf(v);
    } else {
        int t = (blockIdx.x - 1024) * 256 + threadIdx.x;   // 1024
        int h = t >> 8, d = (t >> 1) & 127, which = t & 1;
        const float* av = which ? adw : asw;
        float s = 0.f;
        for (int f = 0; f < 128; f++) s += av[h * 128 + f] * gw[(h * 128 + f) * 128 + d];
        (which ? waD : waS)[h * 128 + d] = s;
    }
}

// ---------------------------------------------------------------------------
// Fused temporal block (R5-verified at ~240 us). BF16=1: final H_temp written
// as bf16 in gat's layout [b][p][c][d] (33.5 MB vs 67 MB f32; gat already
// consumed bf16-rounded values, so results are bit-identical).
#define QKV_STAGE(H, KBB, VTB) do {                                              \
    f32x16 accq, acck, accv;                                                     \
    _Pragma("unroll") for (int r = 0; r < 16; r++)                               \
        accq[r] = bqkv[(H) * 32 + rowmap(r, hl)];                                \
    float bk_ = bqkv[128 + (H) * 32 + l31];                                      \
    float bv_ = bqkv[256 + (H) * 32 + l31];                                      \
    _Pragma("unroll") for (int r = 0; r < 16; r++) { acck[r] = bk_; accv[r] = bv_; } \
    const unsigned short* wq_ = wqkv_b + ((H) * 32 + l31) * 128 + hl * 8;        \
    const unsigned short* wk_ = wqkv_b + (128 + (H) * 32 + l31) * 128 + hl * 8;  \
    const unsigned short* wv_ = wqkv_b + (256 + (H) * 32 + l31) * 128 + hl * 8;  \
    _Pragma("unroll") for (int k0 = 0; k0 < 128; k0 += 16) {                     \
        bf16x8 a_ = lds_frag(&RA[myrow][k0 + hl * 8]);                           \
        accq = MFMA32(gfrag(wq_ + k0), a_, accq);  /* Q^T: rows=dh, cols=toks */ \
        acck = MFMA32(a_, gfrag(wk_ + k0), acck);                                \
        accv = MFMA32(a_, gfrag(wv_ + k0), accv);                                \
    }                                                                            \
    _Pragma("unroll") for (int r = 0; r < 16; r++) {                             \
        int tok_ = wv * 32 + rowmap(r, hl);                                      \
        KBB[tok_][l31] = f2bf(acck[r]);                                          \
        VTB[l31][tok_] = f2bf(accv[r]);                                          \
    }                                                                            \
    qf0_ = pack_frag<0>(accq);                                                   \
    qf1_ = pack_frag<8>(accq);                                                   \
} while (0)

#define ATTN_PHASE(H, KBB, VTB, NEXTQKV) do {                                    \
    f32x16 sacc[4];                                                              \
    _Pragma("unroll") for (int t = 0; t < 4; t++)                                \
    _Pragma("unroll") for (int r = 0; r < 16; r++) sacc[t][r] = 0.f;             \
    _Pragma("unroll") for (int t = 0; t < 4; t++) {                              \
        bf16x8 ka0 = lds_frag(&KBB[t * 32 + l31][hl * 8]);                       \
        sacc[t] = MFMA32(ka0, qf0_, sacc[t]);                                    \
        bf16x8 ka1 = lds_frag(&KBB[t * 32 + l31][16 + hl * 8]);                  \
        sacc[t] = MFMA32(ka1, qf1_, sacc[t]);                                    \
    }                                                                            \
    NEXTQKV;                                                                     \
    const float scale_ = 0.17677669529663687f;   /* 1/sqrt(32) */                \
    float m0 = -1e30f;                                                           \
    _Pragma("unroll") for (int t = 0; t < 4; t++)                                \
    _Pragma("unroll") for (int r = 0; r < 16; r++) m0 = fmaxf(m0, sacc[t][r]);   \
    m0 = fmaxf(m0, __shfl_xor(m0, 32));                                          \
    float ssum = 0.f;                                                            \
    _Pragma("unroll") for (int t = 0; t < 4; t++)                                \
    _Pragma("unroll") for (int r = 0; r < 16; r++) {                             \
        float e_ = __expf(scale_ * (sacc[t][r] - m0));                           \
        sacc[t][r] = e_; ssum += e_;                                             \
    }                                                                            \
    ssum += __shfl_xor(ssum, 32);                                                \
    float rinv_ = 1.f / ssum;                                                    \
    _Pragma("unroll") for (int t = 0; t < 4; t++)                                \
    _Pragma("unroll") for (int r = 0; r < 16; r++) sacc[t][r] *= rinv_;          \
    f32x16 oacc;                                                                 \
    _Pragma("unroll") for (int r = 0; r < 16; r++) oacc[r] = 0.f;                \
    _Pragma("unroll") for (int t = 0; t < 4; t++) {                              \
        bf16x8 pf0 = pack_frag<0>(sacc[t]);                                      \
        bf16x8 v0_ = lds_frag(&VTB[l31][t * 32 + hl * 8]);                       \
        oacc = MFMA32(pf0, v0_, oacc);                                           \
        bf16x8 pf1 = pack_frag<8>(sacc[t]);                                      \
        bf16x8 v1_ = lds_frag(&VTB[l31][t * 32 + 16 + hl * 8]);                  \
        oacc = MFMA32(pf1, v1_, oacc);                                           \
    }                                                                            \
    _Pragma("unroll") for (int j = 0; j < 8; j++)                                \
        opk[H][j] = pk2(oacc[2*j], oacc[2*j+1]);                                 \
} while (0)

template<int BF16>
__global__ __launch_bounds__(256, 2)
void temporal_kernel(const float* __restrict__ Hin,
                     const unsigned short* __restrict__ wqkv_b, const float* __restrict__ bqkv,
                     const unsigned short* __restrict__ wout_b, const float* __restrict__ bout,
                     const float* __restrict__ g1, const float* __restrict__ b1,
                     const float* __restrict__ g2, const float* __restrict__ b2,
                     const unsigned short* __restrict__ w1_b, const float* __restrict__ bf1,
                     const unsigned short* __restrict__ w2_b, const float* __restrict__ bf2,
                     const float* __restrict__ tg, const float* __restrict__ tb,
                     float* __restrict__ Htemp, float* __restrict__ Hs,
                     unsigned short* __restrict__ hbt) {
    // Region A (33792 B): hb (LN1 out) -> O (attn out) -> h2b (LN2 out). Wave-private rows.
    __shared__ unsigned short RA[128][132];
    // Region B (35328 B): attn dbuf {kb0,vT0,kb1,vT1} -> ffn {rscr | hsred}
    __shared__ double RBd[4416];
    unsigned short (*kb0)[36]  = (unsigned short(*)[36])RBd;                       // [tok][dh]
    unsigned short (*vT0)[132] = (unsigned short(*)[132])((char*)RBd + 9216);      // [d][tok]
    unsigned short (*kb1)[36]  = (unsigned short(*)[36])((char*)RBd + 17664);
    unsigned short (*vT1)[132] = (unsigned short(*)[132])((char*)RBd + 26880);
    unsigned short (*rscr)[32][36] = (unsigned short(*)[32][36])RBd;               // [0..9216) = kb0 region
    float (*hsred)[128] = (float(*)[128])((char*)RBd + 9216);                      // [9216..11264) = vT0 region

    const int n = blockIdx.x;
    const int tid = threadIdx.x;
    const int lane = tid & 63;
    const int wv = tid >> 6;
    const int hl = lane >> 5;
    const int l31 = lane & 31;
    const int myrow = wv * 32 + l31;

    // ---- LN1 (wave-private rows: tid>>1 maps wave w to rows w*32..w*32+31) ----
    {
        int row = tid >> 1, hf = tid & 1;
        const float* src = Hin + ((long)n * 128 + row) * 128 + hf * 64;
        float xv[64];
        float s = 0.f, qs = 0.f;
#pragma unroll
        for (int i = 0; i < 64; i += 4) {
            float4 t = *(const float4*)(src + i);
            xv[i] = t.x; xv[i+1] = t.y; xv[i+2] = t.z; xv[i+3] = t.w;
        }
#pragma unroll
        for (int i = 0; i < 64; i++) { s += xv[i]; qs += xv[i] * xv[i]; }
        s += __shfl_xor(s, 1); qs += __shfl_xor(qs, 1);
        float mu = s * 0.0078125f;
        float rs = rsqrtf(fmaxf(qs * 0.0078125f - mu * mu, 0.f) + 1e-5f);
#pragma unroll
        for (int i = 0; i < 64; i++) {
            int d = hf * 64 + i;
            RA[row][d] = f2bf((xv[i] - mu) * rs * g1[d] + b1[d]);
        }
    }
    // no barrier: RA rows are wave-private for QKV A-reads

    unsigned int opk[4][8];   // O, bf16-packed, per head (all indices literal)
    bf16x8 qf0_, qf1_;        // current head's Q fragments

    // ---- pipelined head loop: 1 barrier/head; QKV(h+1) overlaps phase h ----
    QKV_STAGE(0, kb0, vT0);
    __syncthreads();                                   // kb0/vT0 cross-wave
    ATTN_PHASE(0, kb0, vT0, QKV_STAGE(1, kb1, vT1));
    __syncthreads();                                   // kb1/vT1 ready; kb0/vT0 reads done
    ATTN_PHASE(1, kb1, vT1, QKV_STAGE(2, kb0, vT0));
    __syncthreads();
    ATTN_PHASE(2, kb0, vT0, QKV_STAGE(3, kb1, vT1));
    __syncthreads();
    ATTN_PHASE(3, kb1, vT1, (void)0);
    // no barrier: remainder touches only wave-private RA rows + rscr[wv] (kb0
    // region, disjoint from the kb1/vT1 still being read by slower waves).

    // ---- O (packed regs) -> RA (hb dead; wave-private rows) ----
#pragma unroll
    for (int h = 0; h < 4; h++)
#pragma unroll
        for (int j = 0; j < 8; j++) {
            int tok0 = wv * 32 + rowmap(2*j,     hl);
            int tok1 = wv * 32 + rowmap(2*j + 1, hl);
            RA[tok0][h * 32 + l31] = (unsigned short)(opk[h][j] & 0xffffu);
            RA[tok1][h * 32 + l31] = (unsigned short)(opk[h][j] >> 16);
        }

    // ---- x = x0 + bout + O @ Wout^T ----
    f32x16 acc[4];
#pragma unroll
    for (int t = 0; t < 4; t++) {
        float bo = bout[t * 32 + l31];
#pragma unroll
        for (int r = 0; r < 16; r++) {
            int tok = wv * 32 + rowmap(r, hl);
            acc[t][r] = Hin[((long)n * 128 + tok) * 128 + t * 32 + l31] + bo;
        }
    }
#pragma unroll
    for (int k0 = 0; k0 < 128; k0 += 16) {
        bf16x8 a = lds_frag(&RA[myrow][k0 + hl * 8]);
#pragma unroll
        for (int t = 0; t < 4; t++) {
            bf16x8 b = gfrag(wout_b + (t * 32 + l31) * 128 + k0 + hl * 8);
            acc[t] = MFMA32(a, b, acc[t]);
        }
    }

    // ---- LN2 -> RA (h2b; O dead, wave-private rows) ----
#pragma unroll
    for (int r = 0; r < 16; r++) {
        float s = acc[0][r] + acc[1][r] + acc[2][r] + acc[3][r];
#pragma unroll
        for (int d = 1; d < 32; d <<= 1) s += __shfl_xor(s, d);
        float mu = s * 0.0078125f;
        float q = 0.f;
#pragma unroll
        for (int t = 0; t < 4; t++) { float dv = acc[t][r] - mu; q += dv * dv; }
#pragma unroll
        for (int d = 1; d < 32; d <<= 1) q += __shfl_xor(q, d);
        float rs = rsqrtf(q * 0.0078125f + 1e-5f);
        int row = wv * 32 + rowmap(r, hl);
#pragma unroll
        for (int t = 0; t < 4; t++) {
            int col = t * 32 + l31;
            RA[row][col] = f2bf((acc[t][r] - mu) * rs * g2[col] + b2[col]);
        }
    }

    // acc := x + bf2 in place
#pragma unroll
    for (int t = 0; t < 4; t++) {
        float bv = bf2[t * 32 + l31];
#pragma unroll
        for (int r = 0; r < 16; r++) acc[t][r] += bv;
    }

    // ---- FFN in 4 K-chunks of 128; parallel racc tiles, relu via per-wave rscr ----
    for (int j = 0; j < 4; j++) {
        f32x16 racc[4];
#pragma unroll
        for (int t = 0; t < 4; t++) {
            float bv = bf1[j * 128 + t * 32 + l31];
#pragma unroll
            for (int r = 0; r < 16; r++) racc[t][r] = bv;
        }
#pragma unroll
        for (int k0 = 0; k0 < 128; k0 += 16) {
            bf16x8 a = lds_frag(&RA[myrow][k0 + hl * 8]);   // h2b
#pragma unroll
            for (int t = 0; t < 4; t++) {
                bf16x8 b = gfrag(w1_b + (j * 128 + t * 32 + l31) * 128 + k0 + hl * 8);
                racc[t] = MFMA32(a, b, racc[t]);
            }
        }
#pragma unroll
        for (int t = 0; t < 4; t++) {
#pragma unroll
            for (int r = 0; r < 16; r++)
                rscr[wv][rowmap(r, hl)][l31] = f2bf(fmaxf(racc[t][r], 0.f));
#pragma unroll
            for (int kk = 0; kk < 32; kk += 16) {
                bf16x8 a = lds_frag(&rscr[wv][l31][kk + hl * 8]);
#pragma unroll
                for (int tp = 0; tp < 4; tp++) {
                    bf16x8 b = gfrag(w2_b + (tp * 32 + l31) * 512 + j * 128 + t * 32 + kk + hl * 8);
                    acc[tp] = MFMA32(a, b, acc[tp]);
                }
            }
        }
    }

    // ---- H_temp = LN(x0 + x', tg, tb); accumulate Hs column sums ----
#pragma unroll
    for (int t = 0; t < 4; t++)
#pragma unroll
        for (int r = 0; r < 16; r++) {
            int tok = wv * 32 + rowmap(r, hl);
            acc[t][r] += Hin[((long)n * 128 + tok) * 128 + t * 32 + l31];
        }
    const int bb = n >> 6, cc = n & 63;   // n = b*64 + c
    float* outf = Htemp + (long)n * 16384;
    float cs0 = 0.f, cs1 = 0.f, cs2 = 0.f, cs3 = 0.f;
#pragma unroll
    for (int r = 0; r < 16; r++) {
        float s = acc[0][r] + acc[1][r] + acc[2][r] + acc[3][r];
#pragma unroll
        for (int d = 1; d < 32; d <<= 1) s += __shfl_xor(s, d);
        float mu = s * 0.0078125f;
        float q = 0.f;
#pragma unroll
        for (int t = 0; t < 4; t++) { float dv = acc[t][r] - mu; q += dv * dv; }
#pragma unroll
        for (int d = 1; d < 32; d <<= 1) q += __shfl_xor(q, d);
        float rs = rsqrtf(q * 0.0078125f + 1e-5f);
        int tok = wv * 32 + rowmap(r, hl);
        float v0 = (acc[0][r] - mu) * rs * tg[0 * 32 + l31] + tb[0 * 32 + l31];
        float v1 = (acc[1][r] - mu) * rs * tg[1 * 32 + l31] + tb[1 * 32 + l31];
        float v2 = (acc[2][r] - mu) * rs * tg[2 * 32 + l31] + tb[2 * 32 + l31];
        float v3 = (acc[3][r] - mu) * rs * tg[3 * 32 + l31] + tb[3 * 32 + l31];
        cs0 += v0; cs1 += v1; cs2 += v2; cs3 += v3;
        if constexpr (BF16) {
            unsigned short* ob = hbt + ((long)(bb * 128 + tok) * 64 + cc) * 128 + l31;
            ob[0]  = f2bf(v0);
            ob[32] = f2bf(v1);
            ob[64] = f2bf(v2);
            ob[96] = f2bf(v3);
        } else {
            outf[tok * 128 + 0 * 32 + l31] = v0;
            outf[tok * 128 + 1 * 32 + l31] = v1;
            outf[tok * 128 + 2 * 32 + l31] = v2;
            outf[tok * 128 + 3 * 32 + l31] = v3;
        }
    }
    // per-wave: sum own 16 toks + partner-half 16 toks = wave's 32 toks
    cs0 += __shfl_xor(cs0, 32); cs1 += __shfl_xor(cs1, 32);
    cs2 += __shfl_xor(cs2, 32); cs3 += __shfl_xor(cs3, 32);
    if (hl == 0) {
        hsred[wv][0 * 32 + l31] = cs0;
        hsred[wv][1 * 32 + l31] = cs1;
        hsred[wv][2 * 32 + l31] = cs2;
        hsred[wv][3 * 32 + l31] = cs3;
    }
    __syncthreads();
    if (tid < 128)
        Hs[(long)n * 128 + tid] =
            (hsred[0][tid] + hsred[1][tid] + hsred[2][tid] + hsred[3][tid]) * 0.0078125f;
}

// ---------------------------------------------------------------------------
__global__ __launch_bounds__(256)
void graph_kernel(const float* __restrict__ Hs,
                  const float* __restrict__ qw, const float* __restrict__ qb,
                  const float* __restrict__ kw, const float* __restrict__ kb,
                  const float* __restrict__ adj, unsigned long long* __restrict__ masks) {
    __shared__ float q2l[64][65];
    __shared__ float k2l[64][65];
    __shared__ float am[64][65];
    int b = blockIdx.x;
    int tid = threadIdx.x;
    {
        int r = tid & 127, jh = tid >> 7;
        int row = r & 63;
        const float* wmat = (r < 64) ? qw : kw;
        const float* bvec = (r < 64) ? qb : kb;
        const float* src = Hs + (long)(b * 64 + row) * 128;
        for (int jj = 0; jj < 32; jj++) {
            int j = jh * 32 + jj;
            const float* wrow = wmat + (long)j * 128;
            float s0 = 0.f, s1 = 0.f, s2 = 0.f, s3 = 0.f;
#pragma unroll
            for (int d = 0; d < 128; d += 4) {
                s0 += src[d] * wrow[d];     s1 += src[d+1] * wrow[d+1];
                s2 += src[d+2] * wrow[d+2]; s3 += src[d+3] * wrow[d+3];
            }
            float val = ((s0 + s1) + (s2 + s3)) + bvec[j];
            if (r < 64) q2l[row][j] = val; else k2l[row][j] = val;
        }
    }
    __syncthreads();
    {
        int c = tid & 63, eq = tid >> 6;
        for (int ee = 0; ee < 16; ee++) {
            int e = eq * 16 + ee;
            float s0 = 0.f, s1 = 0.f, s2 = 0.f, s3 = 0.f;
#pragma unroll
            for (int j = 0; j < 64; j += 4) {
                s0 += q2l[c][j]   * k2l[e][j];
                s1 += q2l[c][j+1] * k2l[e][j+1];
                s2 += q2l[c][j+2] * k2l[e][j+2];
                s3 += q2l[c][j+3] * k2l[e][j+3];
            }
            float sim = ((s0 + s1) + (s2 + s3)) * 0.125f;
            am[c][e] = tanhf(sim) + adj[c * 64 + e];
        }
    }
    __syncthreads();
    if (tid < 64) {
        int c = tid;
        unsigned long long sel = 0ull;
        for (int it = 0; it < 8; it++) {
            float best = -1e38f; int bi = 0;
            for (int e = 0; e < 64; e++) {
                float v = am[c][e];
                bool ok = (((sel >> e) & 1ull) == 0ull) && (v > best);
                best = ok ? v : best;
                bi = ok ? e : bi;
            }
            sel |= (1ull << bi);
        }
        sel &= ~(1ull << c);
        for (int e = 0; e < 64; e++)
            if (am[c][e] == 0.f) sel &= ~(1ull << e);
        masks[b * 64 + c] = sel;
    }
}

// ---------------------------------------------------------------------------
// GAT + final LN. R6-verified in-register attention weights (e=leaky(asrc+adst)
// is xh-independent; lane owns target rs+l31 and exactly the 32 sources its PV
// A-frags need) + SINGLE-buffered xhT. LDS 38400 B -> 4 blocks/CU (R5: 47.6K->3,
// R6: 55.8K->2 — R6's loss was the second buffer, not the math).
// __launch_bounds__(256,4): gat peak live state ~90-100 regs, fits the 128 cap.
#define XH_STAGE(H, XT) do {                                                     \
    f32x16 a0_, a1_;                                                             \
    _Pragma("unroll") for (int r = 0; r < 16; r++) { a0_[r] = 0.f; a1_[r] = 0.f; } \
    const unsigned short* gwh_ = gwb + (H) * 16384;                              \
    _Pragma("unroll") for (int k0 = 0; k0 < 128; k0 += 16) {                     \
        bf16x8 af_ = lds_frag(&Htb[rs + l31][k0 + hl * 8]);                      \
        bf16x8 b0_ = gfrag(gwh_ + (cs + l31) * 128 + k0 + hl * 8);               \
        bf16x8 b1_ = gfrag(gwh_ + (cs + 32 + l31) * 128 + k0 + hl * 8);          \
        a0_ = MFMA32(af_, b0_, a0_);                                             \
        a1_ = MFMA32(af_, b1_, a1_);                                             \
    }                                                                            \
    _Pragma("unroll") for (int g = 0; g < 4; g++) {                              \
        ushort4 u0_, u1_;                                                        \
        u0_.x = f2bf(a0_[4*g]);   u0_.y = f2bf(a0_[4*g+1]);                      \
        u0_.z = f2bf(a0_[4*g+2]); u0_.w = f2bf(a0_[4*g+3]);                      \
        u1_.x = f2bf(a1_[4*g]);   u1_.y = f2bf(a1_[4*g+1]);                      \
        u1_.z = f2bf(a1_[4*g+2]); u1_.w = f2bf(a1_[4*g+3]);                      \
        int so_ = rs + 4 * hl + 8 * g;                                           \
        *(ushort4*)&XT[cs + l31][so_]      = u0_;                                \
        *(ushort4*)&XT[cs + 32 + l31][so_] = u1_;                                \
    }                                                                            \
} while (0)

#define PV_PHASE(H, XT) do {                                                     \
    float adv_ = adstF[H][rs + l31];   /* target t = rs + l31 */                 \
    float ev_[4][8];                                                             \
    float M_ = -1e30f;                                                           \
    _Pragma("unroll") for (int q = 0; q < 4; q++)                                \
    _Pragma("unroll") for (int j = 0; j < 8; j++) {                              \
        int s_ = q * 16 + hl * 8 + j;                                            \
        float e_ = asrcF[H][s_] + adv_;                                          \
        e_ = (e_ > 0.f) ? e_ : 0.2f * e_;                                        \
        ev_[q][j] = e_;                                                          \
        if ((mt >> s_) & 1ull) M_ = fmaxf(M_, e_);                               \
    }                                                                            \
    M_ = fmaxf(M_, __shfl_xor(M_, 32));                                          \
    float sm_ = 0.f;                                                             \
    _Pragma("unroll") for (int q = 0; q < 4; q++)                                \
    _Pragma("unroll") for (int j = 0; j < 8; j++) {                              \
        int s_ = q * 16 + hl * 8 + j;                                            \
        float w_ = ((mt >> s_) & 1ull) ? __expf(ev_[q][j] - M_) : 0.f;           \
        ev_[q][j] = w_; sm_ += w_;                                               \
    }                                                                            \
    sm_ += __shfl_xor(sm_, 32);                                                  \
    float rinv_ = (sm_ > 0.f) ? 1.f / sm_ : 0.f;                                 \
    _Pragma("unroll") for (int q = 0; q < 4; q++) {                              \
        union { bf16x8 v; unsigned int w[4]; } uu_;                              \
        uu_.w[0] = pk2(ev_[q][0] * rinv_, ev_[q][1] * rinv_);                    \
        uu_.w[1] = pk2(ev_[q][2] * rinv_, ev_[q][3] * rinv_);                    \
        uu_.w[2] = pk2(ev_[q][4] * rinv_, ev_[q][5] * rinv_);                    \
        uu_.w[3] = pk2(ev_[q][6] * rinv_, ev_[q][7] * rinv_);                    \
        bf16x8 af_ = uu_.v;                                                      \
        oacc0 = MFMA32(af_, lds_frag(&XT[cs + l31][q * 16 + hl * 8]), oacc0);    \
        oacc1 = MFMA32(af_, lds_frag(&XT[cs + 32 + l31][q * 16 + hl * 8]), oacc1); \
    }                                                                            \
} while (0)

template<int BF16>
__global__ __launch_bounds__(256, 4)
void gat_kernel(float* __restrict__ Htemp,
                const unsigned short* __restrict__ hbt,
                const unsigned short* __restrict__ gwb,
                const float* __restrict__ waS, const float* __restrict__ waD,
                const float* __restrict__ gbias,
                const unsigned long long* __restrict__ masks,
                const float* __restrict__ sg, const float* __restrict__ sb) {
    __shared__ unsigned short Htb[64][132];        // 16896 B, residual + xh A-operand
    __shared__ double xbuf[2176];                  // 17408 B, xhT (part overlay pre-loop)
    __shared__ float asrcF[4][64], adstF[4][64];   // 2048 B
    __shared__ float pr0[2][64], pr1[2][64];       // 1024 B (final-LN reduce)
    __shared__ unsigned long long mk[64];          // 512 B
    __shared__ unsigned long long mTT[64];         // 512 B (mask transposed: bit s of mTT[t])
    // total 38400 B -> 4 blocks/CU

    unsigned short (*xhT)[68] = (unsigned short(*)[68])xbuf;
    float (*part)[8][64]      = (float(*)[8][64])xbuf;   // overlay, used pre-loop

    const int bp = blockIdx.x;
    const int b = bp >> 7, p = bp & 127;
    const int tid = threadIdx.x;
    const int lane = tid & 63, wv = tid >> 6;
    const int hl = lane >> 5, l31 = lane & 31;
    const int rs = (wv & 1) * 32;
    const int cs = (wv >> 1) * 64;

    if constexpr (BF16) {
        int c = tid >> 2, qq = tid & 3;
        const unsigned short* src = hbt + ((long)(b * 128 + p) * 64 + c) * 128 + qq * 32;
#pragma unroll
        for (int m = 0; m < 8; m++)
            *(ushort4*)&Htb[c][qq * 32 + 4 * m] = *(const ushort4*)(src + 4 * m);
    } else {
        int c = tid >> 2, qq = tid & 3;
        const float* src = Htemp + ((long)(b * 64 + c) * 128 + p) * 128 + qq * 32;
#pragma unroll
        for (int k = 0; k < 8; k++) {
            float4 t4 = *(const float4*)(src + 4 * k);
            ushort4 u; u.x = f2bf(t4.x); u.y = f2bf(t4.y); u.z = f2bf(t4.z); u.w = f2bf(t4.w);
            *(ushort4*)&Htb[c][qq * 32 + 4 * k] = u;
        }
    }
    if (tid < 64) mk[tid] = masks[b * 64 + tid];
    __syncthreads();

    // ---- per-source asrc/adst partials (part overlays xhT; consumed below) ----
    {
        int s = lane, q = wv;
        float acc[8];
#pragma unroll
        for (int m = 0; m < 8; m++) acc[m] = 0.f;
        const unsigned int* hp = (const unsigned int*)&Htb[s][q * 32];
#pragma unroll
        for (int d2 = 0; d2 < 16; d2++) {
            unsigned int u = hp[d2];
            float f0 = __uint_as_float(u << 16);
            float f1 = __uint_as_float(u & 0xffff0000u);
            int d = q * 32 + 2 * d2;
#pragma unroll
            for (int h = 0; h < 4; h++) {
                acc[2*h]   += f0 * waS[h * 128 + d] + f1 * waS[h * 128 + d + 1];
                acc[2*h+1] += f0 * waD[h * 128 + d] + f1 * waD[h * 128 + d + 1];
            }
        }
#pragma unroll
        for (int m = 0; m < 8; m++) part[q][m][s] = acc[m];
    }
    __syncthreads();
    for (int o = tid; o < 512; o += 256) {
        int h = o >> 7, rem = o & 127, which = rem >> 6, s = rem & 63;
        int m = h * 2 + which;
        float v = part[0][m][s] + part[1][m][s] + part[2][m][s] + part[3][m][s];
        if (which == 0) asrcF[h][s] = v; else adstF[h][s] = v;
    }
    // mask transpose: mTT[t] bit s = (mk[s] >> t) & 1
    if (tid < 64) {
        unsigned long long m = 0ull;
        for (int s = 0; s < 64; s++)
            m |= ((mk[s] >> tid) & 1ull) << s;
        mTT[tid] = m;
    }
    __syncthreads();   // asrcF/adstF/mTT ready; part region free for xhT

    const unsigned long long mt = mTT[rs + l31];   // this lane's target mask row

    f32x16 oacc0, oacc1;
#pragma unroll
    for (int r = 0; r < 16; r++) { oacc0[r] = 0.f; oacc1[r] = 0.f; }

    // ---- head loop: single xhT buffer, 2 barriers/head ----
    for (int h = 0; h < 4; h++) {
        XH_STAGE(h, xhT);
        __syncthreads();        // xhT written by all waves
        PV_PHASE(h, xhT);
        __syncthreads();        // all reads done before next head overwrites
    }

    // ---- epilogue: mean over heads, +bias, +residual, final LN ----
    float gb0 = gbias[cs + l31], gb1 = gbias[cs + 32 + l31];
    float v0[16], v1[16];
#pragma unroll
    for (int r = 0; r < 16; r++) {
        int c = rs + rowmap(r, hl);
        v0[r] = oacc0[r] * 0.25f + gb0 + bf2f(Htb[c][cs + l31]);
        v1[r] = oacc1[r] * 0.25f + gb1 + bf2f(Htb[c][cs + 32 + l31]);
    }
#pragma unroll
    for (int r = 0; r < 16; r++) {
        float s = v0[r] + v1[r];
        float q = v0[r] * v0[r] + v1[r] * v1[r];
#pragma unroll
        for (int d = 1; d < 32; d <<= 1) { s += __shfl_xor(s, d); q += __shfl_xor(q, d); }
        if (l31 == 0) {
            int c = rs + rowmap(r, hl);
            pr0[wv >> 1][c] = s;
            pr1[wv >> 1][c] = q;
        }
    }
    __syncthreads();
    float sgv0 = sg[cs + l31], sbv0 = sb[cs + l31];
    float sgv1 = sg[cs + 32 + l31], sbv1 = sb[cs + 32 + l31];
#pragma unroll
    for (int r = 0; r < 16; r++) {
        int c = rs + rowmap(r, hl);
        float sum = pr0[0][c] + pr0[1][c];
        float sq  = pr1[0][c] + pr1[1][c];
        float mu = sum * 0.0078125f;
        float var = sq * 0.0078125f - mu * mu;
        float rsd = rsqrtf(fmaxf(var, 0.f) + 1e-5f);
        float* orow = Htemp + ((long)(b * 64 + c) * 128 + p) * 128;
        orow[cs + l31]      = (v0[r] - mu) * rsd * sgv0 + sbv0;
        orow[cs + 32 + l31] = (v1[r] - mu) * rsd * sgv1 + sbv1;
    }
}

// ---------------------------------------------------------------------------
extern "C" void kernel_launch(void* const* d_in, const int* in_sizes, int n_in,
                              void* d_out, int out_size, void* d_ws, size_t ws_size,
                              hipStream_t stream) {
    const float* Hin        = (const float*)d_in[0];
    const float* static_adj = (const float*)d_in[1];
    const float* attn_in_w  = (const float*)d_in[2];
    const float* attn_in_b  = (const float*)d_in[3];
    const float* attn_out_w = (const float*)d_in[4];
    const float* attn_out_b = (const float*)d_in[5];
    const float* ln1_g      = (const float*)d_in[6];
    const float* ln1_b      = (const float*)d_in[7];
    const float* ln2_g      = (const float*)d_in[8];
    const float* ln2_b      = (const float*)d_in[9];
    const float* ff1_w      = (const float*)d_in[10];
    const float* ff1_b      = (const float*)d_in[11];
    const float* ff2_w      = (const float*)d_in[12];
    const float* ff2_b      = (const float*)d_in[13];
    const float* tnorm_g    = (const float*)d_in[14];
    const float* tnorm_b    = (const float*)d_in[15];
    const float* q_w        = (const float*)d_in[16];
    const float* q_b        = (const float*)d_in[17];
    const float* k_w        = (const float*)d_in[18];
    const float* k_b        = (const float*)d_in[19];
    const float* gat_w      = (const float*)d_in[20];
    const float* gat_att_src= (const float*)d_in[21];
    const float* gat_att_dst= (const float*)d_in[22];
    const float* gat_bias   = (const float*)d_in[23];
    const float* snorm_g    = (const float*)d_in[24];
    const float* snorm_b    = (const float*)d_in[25];

    float* out = (float*)d_out;   // final result (gat writes all of it)
    char* ws = (char*)d_ws;
    unsigned short* wb = (unsigned short*)ws;                 // 524288 B (bf16 weights)
    const unsigned short* wqkv_b = wb;
    const unsigned short* wout_b = wb + 49152;
    const unsigned short* w1_b   = wb + 65536;
    const unsigned short* w2_b   = wb + 131072;
    const unsigned short* gw_b   = wb + 196608;
    unsigned long long* masks = (unsigned long long*)(ws + 524288);   // 8192 B
    float* Hs  = (float*)(ws + 532480);                               // 524288 B
    float* waS = (float*)(ws + 1056768);                              // 2048 B
    float* waD = (float*)(ws + 1058816);                              // 2048 B
    unsigned short* hbt = (unsigned short*)(ws + 1060864);            // 33554432 B (bf16 H_temp, [b][p][c][d])
    const bool big_ws = ws_size >= (size_t)(1060864 + 33554432);

    hipLaunchKernelGGL(prep_kernel, dim3(1028), dim3(256), 0, stream,
                       attn_in_w, attn_out_w, ff1_w, ff2_w, gat_w,
                       gat_att_src, gat_att_dst, wb, waS, waD);
    if (big_ws) {
        hipLaunchKernelGGL((temporal_kernel<1>), dim3(1024), dim3(256), 0, stream,
                           Hin, wqkv_b, attn_in_b, wout_b, attn_out_b,
                           ln1_g, ln1_b, ln2_g, ln2_b,
                           w1_b, ff1_b, w2_b, ff2_b, tnorm_g, tnorm_b, out, Hs, hbt);
        hipLaunchKernelGGL(graph_kernel, dim3(16), dim3(256), 0, stream,
                           Hs, q_w, q_b, k_w, k_b, static_adj, masks);
        hipLaunchKernelGGL((gat_kernel<1>), dim3(2048), dim3(256), 0, stream,
                           out, hbt, gw_b, waS, waD, gat_bias,
                           masks, snorm_g, snorm_b);
    } else {
        hipLaunchKernelGGL((temporal_kernel<0>), dim3(1024), dim3(256), 0, stream,
                           Hin, wqkv_b, attn_in_b, wout_b, attn_out_b,
                           ln1_g, ln1_b, ln2_g, ln2_b,
                           w1_b, ff1_b, w2_b, ff2_b, tnorm_g, tnorm_b, out, Hs, hbt);
        hipLaunchKernelGGL(graph_kernel, dim3(16), dim3(256), 0, stream,
                           Hs, q_w, q_b, k_w, k_b, static_adj, masks);
        hipLaunchKernelGGL((gat_kernel<0>), dim3(2048), dim3(256), 0, stream,
                           out, hbt, gw_b, waS, waD, gat_bias,
                           masks, snorm_g, snorm_b);
    }
}

// Round 11
// 531.301 us; speedup vs baseline: 1.0675x; 1.0015x over previous
//
#include <hip/hip_runtime.h>
#include <cstdint>

// B=16, C=64, Np=128, D=128, HT=4 (dh=32), HS=4, F=128, DK=64, TOPK=8

typedef __attribute__((ext_vector_type(8)))  short bf16x8;
typedef __attribute__((ext_vector_type(16))) float f32x16;
#define MFMA32(a, b, c) __builtin_amdgcn_mfma_f32_32x32x16_bf16((a), (b), (c), 0, 0, 0)

__device__ __forceinline__ unsigned short f2bf(float f) {
    unsigned int u = __float_as_uint(f);
    u += 0x7fffu + ((u >> 16) & 1u);
    return (unsigned short)(u >> 16);
}
__device__ __forceinline__ float bf2f(unsigned short u) {
    return __uint_as_float(((unsigned int)u) << 16);
}

__device__ __forceinline__ bf16x8 lds_frag(const unsigned short* p) {
    union { bf16x8 v; ushort4 h[2]; } u;
    u.h[0] = *(const ushort4*)p;
    u.h[1] = *(const ushort4*)(p + 4);
    return u.v;
}
__device__ __forceinline__ bf16x8 gfrag(const unsigned short* p) {
    union { bf16x8 v; uint4 u; } t;
    t.u = *(const uint4*)p;
    return t.v;
}

// C/D layout for 32x32x16: col = lane&31, row = (reg&3) + 8*(reg>>2) + 4*(lane>>5)
__device__ __forceinline__ int rowmap(int r, int hl) { return (r & 3) + 8 * (r >> 2) + 4 * hl; }

__device__ __forceinline__ unsigned int pk2(float lo, float hi) {
    return (unsigned int)f2bf(lo) | ((unsigned int)f2bf(hi) << 16);
}

// Build an MFMA A/B fragment (16-wide k-chunk) from a C-layout f32x16.
// Partner 4-groups fetched with v_permlane32_swap_b32 (lanes[0:31] <-> lanes[32:63]).
template<int B>
__device__ __forceinline__ bf16x8 pack_frag(const f32x16& p) {
    unsigned int a0 = pk2(p[B + 0], p[B + 1]);
    unsigned int a1 = pk2(p[B + 2], p[B + 3]);
    unsigned int b0 = pk2(p[B + 4], p[B + 5]);
    unsigned int b1 = pk2(p[B + 6], p[B + 7]);
    asm("v_permlane32_swap_b32 %0, %1" : "+v"(b0), "+v"(a0));
    asm("v_permlane32_swap_b32 %0, %1" : "+v"(b1), "+v"(a1));
    union { bf16x8 v; unsigned int w[4]; } u;
    u.w[0] = a0; u.w[1] = a1; u.w[2] = b0; u.w[3] = b1;
    return u.v;
}

// ---------------------------------------------------------------------------
// wconv (1024 blocks) + wa (4 blocks) merged: one launch fewer.
__global__ void prep_kernel(const float* __restrict__ wqkv, const float* __restrict__ wout,
                            const float* __restrict__ w1, const float* __restrict__ w2,
                            const float* __restrict__ gw,
                            const float* __restrict__ asw, const float* __restrict__ adw,
                            unsigned short* __restrict__ dst,
                            float* __restrict__ waS, float* __restrict__ waD) {
    if (blockIdx.x < 1024) {
        int i = blockIdx.x * 256 + threadIdx.x;   // 262144 total
        float v;
        if (i < 49152)       v = wqkv[i];
        else if (i < 65536)  v = wout[i - 49152];
        else if (i < 131072) v = w1[i - 65536];
        else if (i < 196608) v = w2[i - 131072];
        else                 v = gw[i - 196608];
        dst[i] = f2bf(v);
    } else {
        int t = (blockIdx.x - 1024) * 256 + threadIdx.x;   // 1024
        int h = t >> 8, d = (t >> 1) & 127, which = t & 1;
        const float* av = which ? adw : asw;
        float s = 0.f;
        for (int f = 0; f < 128; f++) s += av[h * 128 + f] * gw[(h * 128 + f) * 128 + d];
        (which ? waD : waS)[h * 128 + d] = s;
    }
}

// ---------------------------------------------------------------------------
// Fused temporal block (R5-verified structure). BF16=1: final H_temp written
// as bf16 in gat's layout [b][p][c][d] (33.5 MB vs 67 MB f32; gat already
// consumed bf16-rounded values, so results are bit-identical).
#define QKV_STAGE(H, KBB, VTB) do {                                              \
    f32x16 accq, acck, accv;                                                     \
    _Pragma("unroll") for (int r = 0; r < 16; r++)                               \
        accq[r] = bqkv[(H) * 32 + rowmap(r, hl)];                                \
    float bk_ = bqkv[128 + (H) * 32 + l31];                                      \
    float bv_ = bqkv[256 + (H) * 32 + l31];                                      \
    _Pragma("unroll") for (int r = 0; r < 16; r++) { acck[r] = bk_; accv[r] = bv_; } \
    const unsigned short* wq_ = wqkv_b + ((H) * 32 + l31) * 128 + hl * 8;        \
    const unsigned short* wk_ = wqkv_b + (128 + (H) * 32 + l31) * 128 + hl * 8;  \
    const unsigned short* wv_ = wqkv_b + (256 + (H) * 32 + l31) * 128 + hl * 8;  \
    _Pragma("unroll") for (int k0 = 0; k0 < 128; k0 += 16) {                     \
        bf16x8 a_ = lds_frag(&RA[myrow][k0 + hl * 8]);                           \
        accq = MFMA32(gfrag(wq_ + k0), a_, accq);  /* Q^T: rows=dh, cols=toks */ \
        acck = MFMA32(a_, gfrag(wk_ + k0), acck);                                \
        accv = MFMA32(a_, gfrag(wv_ + k0), accv);                                \
    }                                                                            \
    _Pragma("unroll") for (int r = 0; r < 16; r++) {                             \
        int tok_ = wv * 32 + rowmap(r, hl);                                      \
        KBB[tok_][l31] = f2bf(acck[r]);                                          \
        VTB[l31][tok_] = f2bf(accv[r]);                                          \
    }                                                                            \
    qf0_ = pack_frag<0>(accq);                                                   \
    qf1_ = pack_frag<8>(accq);                                                   \
} while (0)

#define ATTN_PHASE(H, KBB, VTB, NEXTQKV) do {                                    \
    f32x16 sacc[4];                                                              \
    _Pragma("unroll") for (int t = 0; t < 4; t++)                                \
    _Pragma("unroll") for (int r = 0; r < 16; r++) sacc[t][r] = 0.f;             \
    _Pragma("unroll") for (int t = 0; t < 4; t++) {                              \
        bf16x8 ka0 = lds_frag(&KBB[t * 32 + l31][hl * 8]);                       \
        sacc[t] = MFMA32(ka0, qf0_, sacc[t]);                                    \
        bf16x8 ka1 = lds_frag(&KBB[t * 32 + l31][16 + hl * 8]);                  \
        sacc[t] = MFMA32(ka1, qf1_, sacc[t]);                                    \
    }                                                                            \
    NEXTQKV;                                                                     \
    const float scale_ = 0.17677669529663687f;   /* 1/sqrt(32) */                \
    float m0 = -1e30f;                                                           \
    _Pragma("unroll") for (int t = 0; t < 4; t++)                                \
    _Pragma("unroll") for (int r = 0; r < 16; r++) m0 = fmaxf(m0, sacc[t][r]);   \
    m0 = fmaxf(m0, __shfl_xor(m0, 32));                                          \
    float ssum = 0.f;                                                            \
    _Pragma("unroll") for (int t = 0; t < 4; t++)                                \
    _Pragma("unroll") for (int r = 0; r < 16; r++) {                             \
        float e_ = __expf(scale_ * (sacc[t][r] - m0));                           \
        sacc[t][r] = e_; ssum += e_;                                             \
    }                                                                            \
    ssum += __shfl_xor(ssum, 32);                                                \
    float rinv_ = 1.f / ssum;                                                    \
    _Pragma("unroll") for (int t = 0; t < 4; t++)                                \
    _Pragma("unroll") for (int r = 0; r < 16; r++) sacc[t][r] *= rinv_;          \
    f32x16 oacc;                                                                 \
    _Pragma("unroll") for (int r = 0; r < 16; r++) oacc[r] = 0.f;                \
    _Pragma("unroll") for (int t = 0; t < 4; t++) {                              \
        bf16x8 pf0 = pack_frag<0>(sacc[t]);                                      \
        bf16x8 v0_ = lds_frag(&VTB[l31][t * 32 + hl * 8]);                       \
        oacc = MFMA32(pf0, v0_, oacc);                                           \
        bf16x8 pf1 = pack_frag<8>(sacc[t]);                                      \
        bf16x8 v1_ = lds_frag(&VTB[l31][t * 32 + 16 + hl * 8]);                  \
        oacc = MFMA32(pf1, v1_, oacc);                                           \
    }                                                                            \
    _Pragma("unroll") for (int j = 0; j < 8; j++)                                \
        opk[H][j] = pk2(oacc[2*j], oacc[2*j+1]);                                 \
} while (0)

template<int BF16>
__global__ __launch_bounds__(256, 2)
void temporal_kernel(const float* __restrict__ Hin,
                     const unsigned short* __restrict__ wqkv_b, const float* __restrict__ bqkv,
                     const unsigned short* __restrict__ wout_b, const float* __restrict__ bout,
                     const float* __restrict__ g1, const float* __restrict__ b1,
                     const float* __restrict__ g2, const float* __restrict__ b2,
                     const unsigned short* __restrict__ w1_b, const float* __restrict__ bf1,
                     const unsigned short* __restrict__ w2_b, const float* __restrict__ bf2,
                     const float* __restrict__ tg, const float* __restrict__ tb,
                     float* __restrict__ Htemp, float* __restrict__ Hs,
                     unsigned short* __restrict__ hbt) {
    // Region A (33792 B): hb (LN1 out) -> O (attn out) -> h2b (LN2 out). Wave-private rows.
    __shared__ unsigned short RA[128][132];
    // Region B (35328 B): attn dbuf {kb0,vT0,kb1,vT1} -> ffn {rscr | hsred}
    __shared__ double RBd[4416];
    unsigned short (*kb0)[36]  = (unsigned short(*)[36])RBd;                       // [tok][dh]
    unsigned short (*vT0)[132] = (unsigned short(*)[132])((char*)RBd + 9216);      // [d][tok]
    unsigned short (*kb1)[36]  = (unsigned short(*)[36])((char*)RBd + 17664);
    unsigned short (*vT1)[132] = (unsigned short(*)[132])((char*)RBd + 26880);
    unsigned short (*rscr)[32][36] = (unsigned short(*)[32][36])RBd;               // [0..9216) = kb0 region
    float (*hsred)[128] = (float(*)[128])((char*)RBd + 9216);                      // [9216..11264) = vT0 region

    const int n = blockIdx.x;
    const int tid = threadIdx.x;
    const int lane = tid & 63;
    const int wv = tid >> 6;
    const int hl = lane >> 5;
    const int l31 = lane & 31;
    const int myrow = wv * 32 + l31;

    // ---- LN1 (wave-private rows: tid>>1 maps wave w to rows w*32..w*32+31) ----
    {
        int row = tid >> 1, hf = tid & 1;
        const float* src = Hin + ((long)n * 128 + row) * 128 + hf * 64;
        float xv[64];
        float s = 0.f, qs = 0.f;
#pragma unroll
        for (int i = 0; i < 64; i += 4) {
            float4 t = *(const float4*)(src + i);
            xv[i] = t.x; xv[i+1] = t.y; xv[i+2] = t.z; xv[i+3] = t.w;
        }
#pragma unroll
        for (int i = 0; i < 64; i++) { s += xv[i]; qs += xv[i] * xv[i]; }
        s += __shfl_xor(s, 1); qs += __shfl_xor(qs, 1);
        float mu = s * 0.0078125f;
        float rs = rsqrtf(fmaxf(qs * 0.0078125f - mu * mu, 0.f) + 1e-5f);
#pragma unroll
        for (int i = 0; i < 64; i++) {
            int d = hf * 64 + i;
            RA[row][d] = f2bf((xv[i] - mu) * rs * g1[d] + b1[d]);
        }
    }
    // no barrier: RA rows are wave-private for QKV A-reads

    unsigned int opk[4][8];   // O, bf16-packed, per head (all indices literal)
    bf16x8 qf0_, qf1_;        // current head's Q fragments

    // ---- pipelined head loop: 1 barrier/head; QKV(h+1) overlaps phase h ----
    QKV_STAGE(0, kb0, vT0);
    __syncthreads();                                   // kb0/vT0 cross-wave
    ATTN_PHASE(0, kb0, vT0, QKV_STAGE(1, kb1, vT1));
    __syncthreads();                                   // kb1/vT1 ready; kb0/vT0 reads done
    ATTN_PHASE(1, kb1, vT1, QKV_STAGE(2, kb0, vT0));
    __syncthreads();
    ATTN_PHASE(2, kb0, vT0, QKV_STAGE(3, kb1, vT1));
    __syncthreads();
    ATTN_PHASE(3, kb1, vT1, (void)0);
    // no barrier: remainder touches only wave-private RA rows + rscr[wv] (kb0
    // region, disjoint from the kb1/vT1 still being read by slower waves).

    // ---- O (packed regs) -> RA (hb dead; wave-private rows) ----
#pragma unroll
    for (int h = 0; h < 4; h++)
#pragma unroll
        for (int j = 0; j < 8; j++) {
            int tok0 = wv * 32 + rowmap(2*j,     hl);
            int tok1 = wv * 32 + rowmap(2*j + 1, hl);
            RA[tok0][h * 32 + l31] = (unsigned short)(opk[h][j] & 0xffffu);
            RA[tok1][h * 32 + l31] = (unsigned short)(opk[h][j] >> 16);
        }

    // ---- x = x0 + bout + O @ Wout^T ----
    f32x16 acc[4];
#pragma unroll
    for (int t = 0; t < 4; t++) {
        float bo = bout[t * 32 + l31];
#pragma unroll
        for (int r = 0; r < 16; r++) {
            int tok = wv * 32 + rowmap(r, hl);
            acc[t][r] = Hin[((long)n * 128 + tok) * 128 + t * 32 + l31] + bo;
        }
    }
#pragma unroll
    for (int k0 = 0; k0 < 128; k0 += 16) {
        bf16x8 a = lds_frag(&RA[myrow][k0 + hl * 8]);
#pragma unroll
        for (int t = 0; t < 4; t++) {
            bf16x8 b = gfrag(wout_b + (t * 32 + l31) * 128 + k0 + hl * 8);
            acc[t] = MFMA32(a, b, acc[t]);
        }
    }

    // ---- LN2 -> RA (h2b; O dead, wave-private rows) ----
#pragma unroll
    for (int r = 0; r < 16; r++) {
        float s = acc[0][r] + acc[1][r] + acc[2][r] + acc[3][r];
#pragma unroll
        for (int d = 1; d < 32; d <<= 1) s += __shfl_xor(s, d);
        float mu = s * 0.0078125f;
        float q = 0.f;
#pragma unroll
        for (int t = 0; t < 4; t++) { float dv = acc[t][r] - mu; q += dv * dv; }
#pragma unroll
        for (int d = 1; d < 32; d <<= 1) q += __shfl_xor(q, d);
        float rs = rsqrtf(q * 0.0078125f + 1e-5f);
        int row = wv * 32 + rowmap(r, hl);
#pragma unroll
        for (int t = 0; t < 4; t++) {
            int col = t * 32 + l31;
            RA[row][col] = f2bf((acc[t][r] - mu) * rs * g2[col] + b2[col]);
        }
    }

    // acc := x + bf2 in place
#pragma unroll
    for (int t = 0; t < 4; t++) {
        float bv = bf2[t * 32 + l31];
#pragma unroll
        for (int r = 0; r < 16; r++) acc[t][r] += bv;
    }

    // ---- FFN in 4 K-chunks of 128; parallel racc tiles, relu via per-wave rscr ----
    for (int j = 0; j < 4; j++) {
        f32x16 racc[4];
#pragma unroll
        for (int t = 0; t < 4; t++) {
            float bv = bf1[j * 128 + t * 32 + l31];
#pragma unroll
            for (int r = 0; r < 16; r++) racc[t][r] = bv;
        }
#pragma unroll
        for (int k0 = 0; k0 < 128; k0 += 16) {
            bf16x8 a = lds_frag(&RA[myrow][k0 + hl * 8]);   // h2b
#pragma unroll
            for (int t = 0; t < 4; t++) {
                bf16x8 b = gfrag(w1_b + (j * 128 + t * 32 + l31) * 128 + k0 + hl * 8);
                racc[t] = MFMA32(a, b, racc[t]);
            }
        }
#pragma unroll
        for (int t = 0; t < 4; t++) {
#pragma unroll
            for (int r = 0; r < 16; r++)
                rscr[wv][rowmap(r, hl)][l31] = f2bf(fmaxf(racc[t][r], 0.f));
#pragma unroll
            for (int kk = 0; kk < 32; kk += 16) {
                bf16x8 a = lds_frag(&rscr[wv][l31][kk + hl * 8]);
#pragma unroll
                for (int tp = 0; tp < 4; tp++) {
                    bf16x8 b = gfrag(w2_b + (tp * 32 + l31) * 512 + j * 128 + t * 32 + kk + hl * 8);
                    acc[tp] = MFMA32(a, b, acc[tp]);
                }
            }
        }
    }

    // ---- H_temp = LN(x0 + x', tg, tb); accumulate Hs column sums ----
#pragma unroll
    for (int t = 0; t < 4; t++)
#pragma unroll
        for (int r = 0; r < 16; r++) {
            int tok = wv * 32 + rowmap(r, hl);
            acc[t][r] += Hin[((long)n * 128 + tok) * 128 + t * 32 + l31];
        }
    const int bb = n >> 6, cc = n & 63;   // n = b*64 + c
    float* outf = Htemp + (long)n * 16384;
    float cs0 = 0.f, cs1 = 0.f, cs2 = 0.f, cs3 = 0.f;
#pragma unroll
    for (int r = 0; r < 16; r++) {
        float s = acc[0][r] + acc[1][r] + acc[2][r] + acc[3][r];
#pragma unroll
        for (int d = 1; d < 32; d <<= 1) s += __shfl_xor(s, d);
        float mu = s * 0.0078125f;
        float q = 0.f;
#pragma unroll
        for (int t = 0; t < 4; t++) { float dv = acc[t][r] - mu; q += dv * dv; }
#pragma unroll
        for (int d = 1; d < 32; d <<= 1) q += __shfl_xor(q, d);
        float rs = rsqrtf(q * 0.0078125f + 1e-5f);
        int tok = wv * 32 + rowmap(r, hl);
        float v0 = (acc[0][r] - mu) * rs * tg[0 * 32 + l31] + tb[0 * 32 + l31];
        float v1 = (acc[1][r] - mu) * rs * tg[1 * 32 + l31] + tb[1 * 32 + l31];
        float v2 = (acc[2][r] - mu) * rs * tg[2 * 32 + l31] + tb[2 * 32 + l31];
        float v3 = (acc[3][r] - mu) * rs * tg[3 * 32 + l31] + tb[3 * 32 + l31];
        cs0 += v0; cs1 += v1; cs2 += v2; cs3 += v3;
        if constexpr (BF16) {
            unsigned short* ob = hbt + ((long)(bb * 128 + tok) * 64 + cc) * 128 + l31;
            ob[0]  = f2bf(v0);
            ob[32] = f2bf(v1);
            ob[64] = f2bf(v2);
            ob[96] = f2bf(v3);
        } else {
            outf[tok * 128 + 0 * 32 + l31] = v0;
            outf[tok * 128 + 1 * 32 + l31] = v1;
            outf[tok * 128 + 2 * 32 + l31] = v2;
            outf[tok * 128 + 3 * 32 + l31] = v3;
        }
    }
    // per-wave: sum own 16 toks + partner-half 16 toks = wave's 32 toks
    cs0 += __shfl_xor(cs0, 32); cs1 += __shfl_xor(cs1, 32);
    cs2 += __shfl_xor(cs2, 32); cs3 += __shfl_xor(cs3, 32);
    if (hl == 0) {
        hsred[wv][0 * 32 + l31] = cs0;
        hsred[wv][1 * 32 + l31] = cs1;
        hsred[wv][2 * 32 + l31] = cs2;
        hsred[wv][3 * 32 + l31] = cs3;
    }
    __syncthreads();
    if (tid < 128)
        Hs[(long)n * 128 + tid] =
            (hsred[0][tid] + hsred[1][tid] + hsred[2][tid] + hsred[3][tid]) * 0.0078125f;
}

// ---------------------------------------------------------------------------
__global__ __launch_bounds__(256)
void graph_kernel(const float* __restrict__ Hs,
                  const float* __restrict__ qw, const float* __restrict__ qb,
                  const float* __restrict__ kw, const float* __restrict__ kb,
                  const float* __restrict__ adj, unsigned long long* __restrict__ masks) {
    __shared__ float q2l[64][65];
    __shared__ float k2l[64][65];
    __shared__ float am[64][65];
    int b = blockIdx.x;
    int tid = threadIdx.x;
    {
        int r = tid & 127, jh = tid >> 7;
        int row = r & 63;
        const float* wmat = (r < 64) ? qw : kw;
        const float* bvec = (r < 64) ? qb : kb;
        const float* src = Hs + (long)(b * 64 + row) * 128;
        for (int jj = 0; jj < 32; jj++) {
            int j = jh * 32 + jj;
            const float* wrow = wmat + (long)j * 128;
            float s0 = 0.f, s1 = 0.f, s2 = 0.f, s3 = 0.f;
#pragma unroll
            for (int d = 0; d < 128; d += 4) {
                s0 += src[d] * wrow[d];     s1 += src[d+1] * wrow[d+1];
                s2 += src[d+2] * wrow[d+2]; s3 += src[d+3] * wrow[d+3];
            }
            float val = ((s0 + s1) + (s2 + s3)) + bvec[j];
            if (r < 64) q2l[row][j] = val; else k2l[row][j] = val;
        }
    }
    __syncthreads();
    {
        int c = tid & 63, eq = tid >> 6;
        for (int ee = 0; ee < 16; ee++) {
            int e = eq * 16 + ee;
            float s0 = 0.f, s1 = 0.f, s2 = 0.f, s3 = 0.f;
#pragma unroll
            for (int j = 0; j < 64; j += 4) {
                s0 += q2l[c][j]   * k2l[e][j];
                s1 += q2l[c][j+1] * k2l[e][j+1];
                s2 += q2l[c][j+2] * k2l[e][j+2];
                s3 += q2l[c][j+3] * k2l[e][j+3];
            }
            float sim = ((s0 + s1) + (s2 + s3)) * 0.125f;
            am[c][e] = tanhf(sim) + adj[c * 64 + e];
        }
    }
    __syncthreads();
    if (tid < 64) {
        int c = tid;
        unsigned long long sel = 0ull;
        for (int it = 0; it < 8; it++) {
            float best = -1e38f; int bi = 0;
            for (int e = 0; e < 64; e++) {
                float v = am[c][e];
                bool ok = (((sel >> e) & 1ull) == 0ull) && (v > best);
                best = ok ? v : best;
                bi = ok ? e : bi;
            }
            sel |= (1ull << bi);
        }
        sel &= ~(1ull << c);
        for (int e = 0; e < 64; e++)
            if (am[c][e] == 0.f) sel &= ~(1ull << e);
        masks[b * 64 + c] = sel;
    }
}

// ---------------------------------------------------------------------------
// GAT + final LN. In-register attention weights (e=leaky(asrc+adst) is
// xh-independent) + single-buffered xhT. LDS 38400 B -> 4 blocks/CU.
#define XH_STAGE(H, XT) do {                                                     \
    f32x16 a0_, a1_;                                                             \
    _Pragma("unroll") for (int r = 0; r < 16; r++) { a0_[r] = 0.f; a1_[r] = 0.f; } \
    const unsigned short* gwh_ = gwb + (H) * 16384;                              \
    _Pragma("unroll") for (int k0 = 0; k0 < 128; k0 += 16) {                     \
        bf16x8 af_ = lds_frag(&Htb[rs + l31][k0 + hl * 8]);                      \
        bf16x8 b0_ = gfrag(gwh_ + (cs + l31) * 128 + k0 + hl * 8);               \
        bf16x8 b1_ = gfrag(gwh_ + (cs + 32 + l31) * 128 + k0 + hl * 8);          \
        a0_ = MFMA32(af_, b0_, a0_);                                             \
        a1_ = MFMA32(af_, b1_, a1_);                                             \
    }                                                                            \
    _Pragma("unroll") for (int g = 0; g < 4; g++) {                              \
        ushort4 u0_, u1_;                                                        \
        u0_.x = f2bf(a0_[4*g]);   u0_.y = f2bf(a0_[4*g+1]);                      \
        u0_.z = f2bf(a0_[4*g+2]); u0_.w = f2bf(a0_[4*g+3]);                      \
        u1_.x = f2bf(a1_[4*g]);   u1_.y = f2bf(a1_[4*g+1]);                      \
        u1_.z = f2bf(a1_[4*g+2]); u1_.w = f2bf(a1_[4*g+3]);                      \
        int so_ = rs + 4 * hl + 8 * g;                                           \
        *(ushort4*)&XT[cs + l31][so_]      = u0_;                                \
        *(ushort4*)&XT[cs + 32 + l31][so_] = u1_;                                \
    }                                                                            \
} while (0)

#define PV_PHASE(H, XT) do {                                                     \
    float adv_ = adstF[H][rs + l31];   /* target t = rs + l31 */                 \
    float ev_[4][8];                                                             \
    float M_ = -1e30f;                                                           \
    _Pragma("unroll") for (int q = 0; q < 4; q++)                                \
    _Pragma("unroll") for (int j = 0; j < 8; j++) {                              \
        int s_ = q * 16 + hl * 8 + j;                                            \
        float e_ = asrcF[H][s_] + adv_;                                          \
        e_ = (e_ > 0.f) ? e_ : 0.2f * e_;                                        \
        ev_[q][j] = e_;                                                          \
        if ((mt >> s_) & 1ull) M_ = fmaxf(M_, e_);                               \
    }                                                                            \
    M_ = fmaxf(M_, __shfl_xor(M_, 32));                                          \
    float sm_ = 0.f;                                                             \
    _Pragma("unroll") for (int q = 0; q < 4; q++)                                \
    _Pragma("unroll") for (int j = 0; j < 8; j++) {                              \
        int s_ = q * 16 + hl * 8 + j;                                            \
        float w_ = ((mt >> s_) & 1ull) ? __expf(ev_[q][j] - M_) : 0.f;           \
        ev_[q][j] = w_; sm_ += w_;                                               \
    }                                                                            \
    sm_ += __shfl_xor(sm_, 32);                                                  \
    float rinv_ = (sm_ > 0.f) ? 1.f / sm_ : 0.f;                                 \
    _Pragma("unroll") for (int q = 0; q < 4; q++) {                              \
        union { bf16x8 v; unsigned int w[4]; } uu_;                              \
        uu_.w[0] = pk2(ev_[q][0] * rinv_, ev_[q][1] * rinv_);                    \
        uu_.w[1] = pk2(ev_[q][2] * rinv_, ev_[q][3] * rinv_);                    \
        uu_.w[2] = pk2(ev_[q][4] * rinv_, ev_[q][5] * rinv_);                    \
        uu_.w[3] = pk2(ev_[q][6] * rinv_, ev_[q][7] * rinv_);                    \
        bf16x8 af_ = uu_.v;                                                      \
        oacc0 = MFMA32(af_, lds_frag(&XT[cs + l31][q * 16 + hl * 8]), oacc0);    \
        oacc1 = MFMA32(af_, lds_frag(&XT[cs + 32 + l31][q * 16 + hl * 8]), oacc1); \
    }                                                                            \
} while (0)

template<int BF16>
__global__ __launch_bounds__(256, 4)
void gat_kernel(float* __restrict__ Htemp,
                const unsigned short* __restrict__ hbt,
                const unsigned short* __restrict__ gwb,
                const float* __restrict__ waS, const float* __restrict__ waD,
                const float* __restrict__ gbias,
                const unsigned long long* __restrict__ masks,
                const float* __restrict__ sg, const float* __restrict__ sb) {
    __shared__ unsigned short Htb[64][132];        // 16896 B, residual + xh A-operand
    __shared__ double xbuf[2176];                  // 17408 B, xhT (part overlay pre-loop)
    __shared__ float asrcF[4][64], adstF[4][64];   // 2048 B
    __shared__ float pr0[2][64], pr1[2][64];       // 1024 B (final-LN reduce)
    __shared__ unsigned long long mk[64];          // 512 B
    __shared__ unsigned long long mTT[64];         // 512 B (mask transposed: bit s of mTT[t])
    // total 38400 B -> 4 blocks/CU

    unsigned short (*xhT)[68] = (unsigned short(*)[68])xbuf;
    float (*part)[8][64]      = (float(*)[8][64])xbuf;   // overlay, used pre-loop

    const int bp = blockIdx.x;
    const int b = bp >> 7, p = bp & 127;
    const int tid = threadIdx.x;
    const int lane = tid & 63, wv = tid >> 6;
    const int hl = lane >> 5, l31 = lane & 31;
    const int rs = (wv & 1) * 32;
    const int cs = (wv >> 1) * 64;

    if constexpr (BF16) {
        int c = tid >> 2, qq = tid & 3;
        const unsigned short* src = hbt + ((long)(b * 128 + p) * 64 + c) * 128 + qq * 32;
#pragma unroll
        for (int m = 0; m < 8; m++)
            *(ushort4*)&Htb[c][qq * 32 + 4 * m] = *(const ushort4*)(src + 4 * m);
    } else {
        int c = tid >> 2, qq = tid & 3;
        const float* src = Htemp + ((long)(b * 64 + c) * 128 + p) * 128 + qq * 32;
#pragma unroll
        for (int k = 0; k < 8; k++) {
            float4 t4 = *(const float4*)(src + 4 * k);
            ushort4 u; u.x = f2bf(t4.x); u.y = f2bf(t4.y); u.z = f2bf(t4.z); u.w = f2bf(t4.w);
            *(ushort4*)&Htb[c][qq * 32 + 4 * k] = u;
        }
    }
    if (tid < 64) mk[tid] = masks[b * 64 + tid];
    __syncthreads();

    // ---- per-source asrc/adst partials (part overlays xhT; consumed below) ----
    {
        int s = lane, q = wv;
        float acc[8];
#pragma unroll
        for (int m = 0; m < 8; m++) acc[m] = 0.f;
        const unsigned int* hp = (const unsigned int*)&Htb[s][q * 32];
#pragma unroll
        for (int d2 = 0; d2 < 16; d2++) {
            unsigned int u = hp[d2];
            float f0 = __uint_as_float(u << 16);
            float f1 = __uint_as_float(u & 0xffff0000u);
            int d = q * 32 + 2 * d2;
#pragma unroll
            for (int h = 0; h < 4; h++) {
                acc[2*h]   += f0 * waS[h * 128 + d] + f1 * waS[h * 128 + d + 1];
                acc[2*h+1] += f0 * waD[h * 128 + d] + f1 * waD[h * 128 + d + 1];
            }
        }
#pragma unroll
        for (int m = 0; m < 8; m++) part[q][m][s] = acc[m];
    }
    __syncthreads();
    for (int o = tid; o < 512; o += 256) {
        int h = o >> 7, rem = o & 127, which = rem >> 6, s = rem & 63;
        int m = h * 2 + which;
        float v = part[0][m][s] + part[1][m][s] + part[2][m][s] + part[3][m][s];
        if (which == 0) asrcF[h][s] = v; else adstF[h][s] = v;
    }
    // mask transpose: mTT[t] bit s = (mk[s] >> t) & 1
    if (tid < 64) {
        unsigned long long m = 0ull;
        for (int s = 0; s < 64; s++)
            m |= ((mk[s] >> tid) & 1ull) << s;
        mTT[tid] = m;
    }
    __syncthreads();   // asrcF/adstF/mTT ready; part region free for xhT

    const unsigned long long mt = mTT[rs + l31];   // this lane's target mask row

    f32x16 oacc0, oacc1;
#pragma unroll
    for (int r = 0; r < 16; r++) { oacc0[r] = 0.f; oacc1[r] = 0.f; }

    // ---- head loop: single xhT buffer, 2 barriers/head ----
    for (int h = 0; h < 4; h++) {
        XH_STAGE(h, xhT);
        __syncthreads();        // xhT written by all waves
        PV_PHASE(h, xhT);
        __syncthreads();        // all reads done before next head overwrites
    }

    // ---- epilogue: mean over heads, +bias, +residual, final LN ----
    float gb0 = gbias[cs + l31], gb1 = gbias[cs + 32 + l31];
    float v0[16], v1[16];
#pragma unroll
    for (int r = 0; r < 16; r++) {
        int c = rs + rowmap(r, hl);
        v0[r] = oacc0[r] * 0.25f + gb0 + bf2f(Htb[c][cs + l31]);
        v1[r] = oacc1[r] * 0.25f + gb1 + bf2f(Htb[c][cs + 32 + l31]);
    }
#pragma unroll
    for (int r = 0; r < 16; r++) {
        float s = v0[r] + v1[r];
        float q = v0[r] * v0[r] + v1[r] * v1[r];
#pragma unroll
        for (int d = 1; d < 32; d <<= 1) { s += __shfl_xor(s, d); q += __shfl_xor(q, d); }
        if (l31 == 0) {
            int c = rs + rowmap(r, hl);
            pr0[wv >> 1][c] = s;
            pr1[wv >> 1][c] = q;
        }
    }
    __syncthreads();
    float sgv0 = sg[cs + l31], sbv0 = sb[cs + l31];
    float sgv1 = sg[cs + 32 + l31], sbv1 = sb[cs + 32 + l31];
#pragma unroll
    for (int r = 0; r < 16; r++) {
        int c = rs + rowmap(r, hl);
        float sum = pr0[0][c] + pr0[1][c];
        float sq  = pr1[0][c] + pr1[1][c];
        float mu = sum * 0.0078125f;
        float var = sq * 0.0078125f - mu * mu;
        float rsd = rsqrtf(fmaxf(var, 0.f) + 1e-5f);
        float* orow = Htemp + ((long)(b * 64 + c) * 128 + p) * 128;
        orow[cs + l31]      = (v0[r] - mu) * rsd * sgv0 + sbv0;
        orow[cs + 32 + l31] = (v1[r] - mu) * rsd * sgv1 + sbv1;
    }
}

// ---------------------------------------------------------------------------
extern "C" void kernel_launch(void* const* d_in, const int* in_sizes, int n_in,
                              void* d_out, int out_size, void* d_ws, size_t ws_size,
                              hipStream_t stream) {
    const float* Hin        = (const float*)d_in[0];
    const float* static_adj = (const float*)d_in[1];
    const float* attn_in_w  = (const float*)d_in[2];
    const float* attn_in_b  = (const float*)d_in[3];
    const float* attn_out_w = (const float*)d_in[4];
    const float* attn_out_b = (const float*)d_in[5];
    const float* ln1_g      = (const float*)d_in[6];
    const float* ln1_b      = (const float*)d_in[7];
    const float* ln2_g      = (const float*)d_in[8];
    const float* ln2_b      = (const float*)d_in[9];
    const float* ff1_w      = (const float*)d_in[10];
    const float* ff1_b      = (const float*)d_in[11];
    const float* ff2_w      = (const float*)d_in[12];
    const float* ff2_b      = (const float*)d_in[13];
    const float* tnorm_g    = (const float*)d_in[14];
    const float* tnorm_b    = (const float*)d_in[15];
    const float* q_w        = (const float*)d_in[16];
    const float* q_b        = (const float*)d_in[17];
    const float* k_w        = (const float*)d_in[18];
    const float* k_b        = (const float*)d_in[19];
    const float* gat_w      = (const float*)d_in[20];
    const float* gat_att_src= (const float*)d_in[21];
    const float* gat_att_dst= (const float*)d_in[22];
    const float* gat_bias   = (const float*)d_in[23];
    const float* snorm_g    = (const float*)d_in[24];
    const float* snorm_b    = (const float*)d_in[25];

    float* out = (float*)d_out;   // final result (gat writes all of it)
    char* ws = (char*)d_ws;
    unsigned short* wb = (unsigned short*)ws;                 // 524288 B (bf16 weights)
    const unsigned short* wqkv_b = wb;
    const unsigned short* wout_b = wb + 49152;
    const unsigned short* w1_b   = wb + 65536;
    const unsigned short* w2_b   = wb + 131072;
    const unsigned short* gw_b   = wb + 196608;
    unsigned long long* masks = (unsigned long long*)(ws + 524288);   // 8192 B
    float* Hs  = (float*)(ws + 532480);                               // 524288 B
    float* waS = (float*)(ws + 1056768);                              // 2048 B
    float* waD = (float*)(ws + 1058816);                              // 2048 B
    unsigned short* hbt = (unsigned short*)(ws + 1060864);            // 33554432 B (bf16 H_temp, [b][p][c][d])
    const bool big_ws = ws_size >= (size_t)(1060864 + 33554432);

    hipLaunchKernelGGL(prep_kernel, dim3(1028), dim3(256), 0, stream,
                       attn_in_w, attn_out_w, ff1_w, ff2_w, gat_w,
                       gat_att_src, gat_att_dst, wb, waS, waD);
    if (big_ws) {
        hipLaunchKernelGGL((temporal_kernel<1>), dim3(1024), dim3(256), 0, stream,
                           Hin, wqkv_b, attn_in_b, wout_b, attn_out_b,
                           ln1_g, ln1_b, ln2_g, ln2_b,
                           w1_b, ff1_b, w2_b, ff2_b, tnorm_g, tnorm_b, out, Hs, hbt);
        hipLaunchKernelGGL(graph_kernel, dim3(16), dim3(256), 0, stream,
                           Hs, q_w, q_b, k_w, k_b, static_adj, masks);
        hipLaunchKernelGGL((gat_kernel<1>), dim3(2048), dim3(256), 0, stream,
                           out, hbt, gw_b, waS, waD, gat_bias,
                           masks, snorm_g, snorm_b);
    } else {
        hipLaunchKernelGGL((temporal_kernel<0>), dim3(1024), dim3(256), 0, stream,
                           Hin, wqkv_b, attn_in_b, wout_b, attn_out_b,
                           ln1_g, ln1_b, ln2_g, ln2_b,
                           w1_b, ff1_b, w2_b, ff2_b, tnorm_g, tnorm_b, out, Hs, hbt);
        hipLaunchKernelGGL(graph_kernel, dim3(16), dim3(256), 0, stream,
                           Hs, q_w, q_b, k_w, k_b, static_adj, masks);
        hipLaunchKernelGGL((gat_kernel<0>), dim3(2048), dim3(256), 0, stream,
                           out, hbt, gw_b, waS, waD, gat_bias,
                           masks, snorm_g, snorm_b);
    }
}